// Round 4
// baseline (1120.716 us; speedup 1.0000x reference)
//
#include <hip/hip_runtime.h>
#include <hip/hip_bf16.h>

constexpr int DIN = 16;
constexpr int D   = 256;
constexpr int NH  = 8;
constexpr int NC  = 32;
constexpr int MC  = 200;
constexpr int NT  = 8;
constexpr int BG  = 16;
constexpr int NL  = 6;
constexpr float NEG = 0.2f;

// block-wide (256-thread) sum, LDS tree, result broadcast to all threads.
__device__ inline float blocksum256(float v, float* rbuf, int t) {
    __syncthreads();               // protect rbuf from previous use
    rbuf[t] = v;
    __syncthreads();
    if (t < 128) rbuf[t] += rbuf[t + 128]; __syncthreads();
    if (t < 64)  rbuf[t] += rbuf[t + 64];  __syncthreads();
    if (t < 32)  rbuf[t] += rbuf[t + 32];  __syncthreads();
    if (t < 16)  rbuf[t] += rbuf[t + 16];  __syncthreads();
    if (t < 8)   rbuf[t] += rbuf[t + 8];   __syncthreads();
    if (t < 4)   rbuf[t] += rbuf[t + 4];   __syncthreads();
    if (t < 2)   rbuf[t] += rbuf[t + 2];   __syncthreads();
    if (t < 1)   rbuf[t] += rbuf[t + 1];   __syncthreads();
    float r = rbuf[0];
    __syncthreads();
    return r;
}

// ---------------------------------------------------------------- init
__global__ __launch_bounds__(256) void init_k(int* __restrict__ deg, float* __restrict__ msum,
                                              unsigned* __restrict__ mkey, int* __restrict__ cnt, int N) {
    int i = blockIdx.x * 256 + threadIdx.x;
    if (i < N) deg[i] = 1;                 // self-loop pre-counted
    if (i < BG * D) { msum[i] = 0.f; mkey[i] = 0u; }
    if (i < BG) cnt[i] = 0;
}

// ---------------------------------------------------------------- encoder: h = relu(LN(x@W+b))
__global__ __launch_bounds__(256) void enc_k(const float* __restrict__ x, const float* __restrict__ W,
                                             const float* __restrict__ b, const float* __restrict__ ls,
                                             const float* __restrict__ lb, float* __restrict__ h, int N) {
    int n = blockIdx.x, t = threadIdx.x;
    __shared__ float xs[DIN];
    __shared__ float rbuf[256];
    if (t < DIN) xs[t] = x[n * DIN + t];
    __syncthreads();
    float acc = b[t];
#pragma unroll
    for (int k = 0; k < DIN; k++) acc = fmaf(xs[k], W[k * D + t], acc);
    float mu = blocksum256(acc, rbuf, t) * (1.f / D);
    float d = acc - mu;
    float var = blocksum256(d * d, rbuf, t) * (1.f / D);
    float rstd = rsqrtf(var + 1e-5f);
    float y = d * rstd * ls[t] + lb[t];
    h[(size_t)n * D + t] = fmaxf(y, 0.f);
}

// ---------------------------------------------------------------- CSR build
__global__ __launch_bounds__(256) void count_k(const int* __restrict__ dst, int* __restrict__ deg, int E) {
    int e = blockIdx.x * 256 + threadIdx.x;
    if (e < E) atomicAdd(&deg[dst[e]], 1);
}

__global__ __launch_bounds__(1024) void scan_k(const int* __restrict__ deg, int* __restrict__ row_ptr,
                                               int* __restrict__ fill, int N) {
    __shared__ int sd[1024];
    int t = threadIdx.x;
    int chunk = (N + 1023) >> 10;
    int lo = t * chunk, hi = min(lo + chunk, N);
    int s = 0;
    for (int i = lo; i < hi; i++) s += deg[i];
    sd[t] = s;
    __syncthreads();
    for (int off = 1; off < 1024; off <<= 1) {
        int v = (t >= off) ? sd[t - off] : 0;
        __syncthreads();
        sd[t] += v;
        __syncthreads();
    }
    int run = (t > 0) ? sd[t - 1] : 0;
    for (int i = lo; i < hi; i++) {
        row_ptr[i] = run; fill[i] = run;
        run += deg[i];
    }
    if (t == 1023) row_ptr[N] = sd[1023];
}

__global__ __launch_bounds__(256) void scatter_k(const int* __restrict__ src, const int* __restrict__ dst,
                                                 int* __restrict__ fill, int* __restrict__ col, int E, int N) {
    int e = blockIdx.x * 256 + threadIdx.x;
    if (e < E) {
        int p = atomicAdd(&fill[dst[e]], 1);
        col[p] = src[e];
    } else if (e < E + N) {
        int n = e - E;
        int p = atomicAdd(&fill[n], 1);
        col[p] = n;                       // self loop
    }
}

// ---------------------------------------------------------------- xl = h@Wl+bl, xr = h@Wr+br  (8 nodes/block)
__global__ __launch_bounds__(256) void gemm_lr_k(const float* __restrict__ h,
                                                 const float* __restrict__ Wl, const float* __restrict__ bl,
                                                 const float* __restrict__ Wr, const float* __restrict__ br,
                                                 float* __restrict__ xl, float* __restrict__ xr, int N) {
    int t = threadIdx.x;
    int nb = blockIdx.x * 8;
    int nmax = min(8, N - nb);
    __shared__ float hs[8][D];
    for (int r = 0; r < 8; r++) hs[r][t] = (r < nmax) ? h[(size_t)(nb + r) * D + t] : 0.f;
    __syncthreads();
    float accl[8], accr[8];
    float blv = bl[t], brv = br[t];
#pragma unroll
    for (int r = 0; r < 8; r++) { accl[r] = blv; accr[r] = brv; }
    for (int k = 0; k < D; k++) {
        float wl = Wl[k * D + t];
        float wr = Wr[k * D + t];
#pragma unroll
        for (int r = 0; r < 8; r++) {
            accl[r] = fmaf(hs[r][k], wl, accl[r]);
            accr[r] = fmaf(hs[r][k], wr, accr[r]);
        }
    }
    for (int r = 0; r < nmax; r++) {
        xl[(size_t)(nb + r) * D + t] = accl[r];
        xr[(size_t)(nb + r) * D + t] = accr[r];
    }
}

// ---------------------------------------------------------------- fused GATv2 layer: attention (online
//   softmax) + aggregate + bias + LN + ELU + residual. One block per dst node; t=(head t/32, chan t%32).
__global__ __launch_bounds__(256) void attn_k(const float* __restrict__ xl, const float* __restrict__ xr,
                                              const int* __restrict__ row_ptr, const int* __restrict__ col,
                                              const float* __restrict__ att, const float* __restrict__ gb,
                                              const float* __restrict__ gls, const float* __restrict__ glb,
                                              float* __restrict__ h, int layer, int N) {
    int n = blockIdx.x, t = threadIdx.x;
    __shared__ float sbuf[256];
    float xrv = xr[(size_t)n * D + t];
    float attv = att[t];
    int beg = row_ptr[n], end = row_ptr[n + 1];
    float m = -3.0e38f, l = 0.f, acc = 0.f;
    for (int e = beg; e < end; e++) {
        int src = col[e];
        float xlv = xl[(size_t)src * D + t];
        float sv = xlv + xrv;
        sv = sv > 0.f ? sv : NEG * sv;
        sbuf[t] = attv * sv;
        __syncthreads();
        // per-head (aligned 32-thread group) tree reduction
        if ((t & 31) < 16) sbuf[t] += sbuf[t + 16]; __syncthreads();
        if ((t & 31) < 8)  sbuf[t] += sbuf[t + 8];  __syncthreads();
        if ((t & 31) < 4)  sbuf[t] += sbuf[t + 4];  __syncthreads();
        if ((t & 31) < 2)  sbuf[t] += sbuf[t + 2];  __syncthreads();
        if ((t & 31) < 1)  sbuf[t] += sbuf[t + 1];  __syncthreads();
        float z = sbuf[t & ~31];
        __syncthreads();             // before next edge overwrites sbuf
        float mn = fmaxf(m, z);
        float sc = __expf(m - mn);
        float p  = __expf(z - mn);
        l   = l * sc + p;
        acc = acc * sc + p * xlv;
        m = mn;
    }
    float outv = acc / l + gb[t];
    // LayerNorm over 256 dims, two-pass (matches reference; var >= 0 by construction)
    float mu = blocksum256(outv, sbuf, t) * (1.f / D);
    float dv = outv - mu;
    float var = blocksum256(dv * dv, sbuf, t) * (1.f / D);
    float rstd = rsqrtf(var + 1e-5f);
    float y = dv * rstd * gls[t] + glb[t];
    float eluv = y > 0.f ? y : expm1f(y);
    float prev = (layer > 0) ? h[(size_t)n * D + t] : 0.f;
    h[(size_t)n * D + t] = prev + eluv;
}

// ---------------------------------------------------------------- per-node color head MLP (8 nodes/block)
__global__ __launch_bounds__(256) void color_k(const float* __restrict__ h,
                                               const float* __restrict__ W1, const float* __restrict__ b1,
                                               const float* __restrict__ W2, const float* __restrict__ b2,
                                               const float* __restrict__ W3, const float* __restrict__ b3,
                                               float* __restrict__ out, int N) {
    int t = threadIdx.x;
    int nb = blockIdx.x * 8;
    int nmax = min(8, N - nb);
    __shared__ float hs[8][D];
    __shared__ float z1[8][D];
    __shared__ float z2[8][128];
    for (int r = 0; r < 8; r++) hs[r][t] = (r < nmax) ? h[(size_t)(nb + r) * D + t] : 0.f;
    __syncthreads();
    float a[8];
    {
        float bv = b1[t];
#pragma unroll
        for (int r = 0; r < 8; r++) a[r] = bv;
        for (int k = 0; k < D; k++) {
            float w = W1[k * D + t];
#pragma unroll
            for (int r = 0; r < 8; r++) a[r] = fmaf(hs[r][k], w, a[r]);
        }
        for (int r = 0; r < 8; r++) z1[r][t] = fmaxf(a[r], 0.f);
    }
    __syncthreads();
    if (t < 128) {
        float bv = b2[t];
#pragma unroll
        for (int r = 0; r < 8; r++) a[r] = bv;
        for (int k = 0; k < D; k++) {
            float w = W2[k * 128 + t];
#pragma unroll
            for (int r = 0; r < 8; r++) a[r] = fmaf(z1[r][k], w, a[r]);
        }
        for (int r = 0; r < 8; r++) z2[r][t] = fmaxf(a[r], 0.f);
    }
    __syncthreads();
    if (t < MC) {
        float bv = b3[t];
#pragma unroll
        for (int r = 0; r < 8; r++) a[r] = bv;
        for (int k = 0; k < 128; k++) {
            float w = W3[k * MC + t];
#pragma unroll
            for (int r = 0; r < 8; r++) a[r] = fmaf(z2[r][k], w, a[r]);
        }
        for (int r = 0; r < nmax; r++) out[(size_t)(nb + r) * MC + t] = a[r];
    }
}

// ---------------------------------------------------------------- pooling: segment mean-sum / max / count
__global__ __launch_bounds__(256) void pool_k(const float* __restrict__ h, const int* __restrict__ batch,
                                              float* __restrict__ msum, unsigned* __restrict__ mkey,
                                              int* __restrict__ cnt, int N) {
    int n = blockIdx.x, t = threadIdx.x;
    int b = batch[n];
    float v = h[(size_t)n * D + t];
    atomicAdd(&msum[b * D + t], v);
    unsigned bits = __float_as_uint(v);
    unsigned key = (bits & 0x80000000u) ? ~bits : (bits | 0x80000000u);  // monotone float->uint
    atomicMax(&mkey[b * D + t], key);
    if (t == 0) atomicAdd(&cnt[b], 1);
}

// ---------------------------------------------------------------- graph heads (one block per graph)
__global__ __launch_bounds__(256) void heads_k(const float* __restrict__ msum, const unsigned* __restrict__ mkey,
                                               const int* __restrict__ cnt,
                                               const float* __restrict__ chW1, const float* __restrict__ chb1,
                                               const float* __restrict__ chW2, const float* __restrict__ chb2,
                                               const float* __restrict__ chW3, const float* __restrict__ chb3,
                                               const float* __restrict__ tW1, const float* __restrict__ tb1,
                                               const float* __restrict__ tW2, const float* __restrict__ tb2,
                                               const float* __restrict__ dW1, const float* __restrict__ db1,
                                               const float* __restrict__ dW2, const float* __restrict__ db2,
                                               float* __restrict__ out_ch, float* __restrict__ out_t,
                                               float* __restrict__ out_d) {
    int b = blockIdx.x, t = threadIdx.x;
    __shared__ float g[2 * D];
    __shared__ float z1[D];
    __shared__ float z2[128];
    float c = fmaxf((float)cnt[b], 1.f);
    g[t] = msum[b * D + t] / c;
    unsigned key = mkey[b * D + t];
    float mv = 0.f;
    if (key != 0u) {
        unsigned bits = (key & 0x80000000u) ? (key ^ 0x80000000u) : ~key;
        mv = __uint_as_float(bits);
    }
    g[D + t] = mv;
    __syncthreads();
    // chromatic head: 512 -> 256 -> 128 -> MC
    float a = chb1[t];
    for (int k = 0; k < 2 * D; k++) a = fmaf(g[k], chW1[k * D + t], a);
    z1[t] = fmaxf(a, 0.f);
    __syncthreads();
    if (t < 128) {
        a = chb2[t];
        for (int k = 0; k < D; k++) a = fmaf(z1[k], chW2[k * 128 + t], a);
        z2[t] = fmaxf(a, 0.f);
    }
    __syncthreads();
    if (t < MC) {
        a = chb3[t];
        for (int k = 0; k < 128; k++) a = fmaf(z2[k], chW3[k * MC + t], a);
        out_ch[b * MC + t] = a;
    }
    __syncthreads();
    // type head: 512 -> 128 -> NT
    if (t < 128) {
        a = tb1[t];
        for (int k = 0; k < 2 * D; k++) a = fmaf(g[k], tW1[k * 128 + t], a);
        z1[t] = fmaxf(a, 0.f);
    }
    __syncthreads();
    if (t < NT) {
        a = tb2[t];
        for (int k = 0; k < 128; k++) a = fmaf(z1[k], tW2[k * NT + t], a);
        out_t[b * NT + t] = a;
    }
    __syncthreads();
    // difficulty head: 512 -> 64 -> 1, sigmoid*100
    if (t < 64) {
        a = db1[t];
        for (int k = 0; k < 2 * D; k++) a = fmaf(g[k], dW1[k * 64 + t], a);
        z1[t] = fmaxf(a, 0.f);
    }
    __syncthreads();
    if (t == 0) {
        a = db2[0];
        for (int k = 0; k < 64; k++) a = fmaf(z1[k], dW2[k], a);
        float sg = 1.f / (1.f + __expf(-a));
        out_d[b] = 100.f * sg;
    }
}

// ----------------------------------------------------------------
extern "C" void kernel_launch(void* const* d_in, const int* in_sizes, int n_in,
                              void* d_out, int out_size, void* d_ws, size_t ws_size,
                              hipStream_t stream) {
    const float* x     = (const float*)d_in[0];
    const int*   ei    = (const int*)d_in[1];
    const int*   batch = (const int*)d_in[2];
    const float* encW  = (const float*)d_in[3];
    const float* encb  = (const float*)d_in[4];
    const float* encls = (const float*)d_in[5];
    const float* enclb = (const float*)d_in[6];
    const float* Wl    = (const float*)d_in[7];
    const float* bl    = (const float*)d_in[8];
    const float* Wr    = (const float*)d_in[9];
    const float* br    = (const float*)d_in[10];
    const float* att   = (const float*)d_in[11];
    const float* gb    = (const float*)d_in[12];
    const float* gls   = (const float*)d_in[13];
    const float* glb   = (const float*)d_in[14];
    const float* cW1   = (const float*)d_in[15];
    const float* cb1   = (const float*)d_in[16];
    const float* cW2   = (const float*)d_in[17];
    const float* cb2   = (const float*)d_in[18];
    const float* cW3   = (const float*)d_in[19];
    const float* cb3   = (const float*)d_in[20];
    const float* chW1  = (const float*)d_in[21];
    const float* chb1  = (const float*)d_in[22];
    const float* chW2  = (const float*)d_in[23];
    const float* chb2  = (const float*)d_in[24];
    const float* chW3  = (const float*)d_in[25];
    const float* chb3  = (const float*)d_in[26];
    const float* tW1   = (const float*)d_in[27];
    const float* tb1   = (const float*)d_in[28];
    const float* tW2   = (const float*)d_in[29];
    const float* tb2   = (const float*)d_in[30];
    const float* dW1   = (const float*)d_in[31];
    const float* db1   = (const float*)d_in[32];
    const float* dW2   = (const float*)d_in[33];
    const float* db2   = (const float*)d_in[34];

    const int N = in_sizes[0] / DIN;
    const int E = in_sizes[1] / 2;
    const int* esrc = ei;
    const int* edst = ei + E;

    // workspace carve-up: small arrays first, big feature arrays last
    char* p = (char*)d_ws;
    auto carve = [&](size_t bytes) { char* r = p; p += (bytes + 255) & ~(size_t)255; return r; };
    int*      row_ptr = (int*)carve((size_t)(N + 1) * 4);
    int*      fill    = (int*)carve((size_t)N * 4);
    int*      deg     = (int*)carve((size_t)N * 4);
    int*      cnt     = (int*)carve((size_t)BG * 4);
    float*    msum    = (float*)carve((size_t)BG * D * 4);
    unsigned* mkey    = (unsigned*)carve((size_t)BG * D * 4);
    int*      col     = (int*)carve((size_t)(E + N) * 4);
    float*    h       = (float*)carve((size_t)N * D * 4);
    float*    xl      = (float*)carve((size_t)N * D * 4);
    float*    xr      = (float*)carve((size_t)N * D * 4);
    (void)ws_size; (void)n_in; (void)out_size;

    init_k<<<(N + 255) / 256, 256, 0, stream>>>(deg, msum, mkey, cnt, N);
    enc_k<<<N, 256, 0, stream>>>(x, encW, encb, encls, enclb, h, N);
    count_k<<<(E + 255) / 256, 256, 0, stream>>>(edst, deg, E);
    scan_k<<<1, 1024, 0, stream>>>(deg, row_ptr, fill, N);
    scatter_k<<<(E + N + 255) / 256, 256, 0, stream>>>(esrc, edst, fill, col, E, N);

    for (int i = 0; i < NL; i++) {
        gemm_lr_k<<<(N + 7) / 8, 256, 0, stream>>>(h, Wl + (size_t)i * D * D, bl + i * D,
                                                   Wr + (size_t)i * D * D, br + i * D, xl, xr, N);
        attn_k<<<N, 256, 0, stream>>>(xl, xr, row_ptr, col, att + i * NH * NC,
                                      gb + i * D, gls + i * D, glb + i * D, h, i, N);
    }

    float* out = (float*)d_out;
    color_k<<<(N + 7) / 8, 256, 0, stream>>>(h, cW1, cb1, cW2, cb2, cW3, cb3, out, N);
    pool_k<<<N, 256, 0, stream>>>(h, batch, msum, mkey, cnt, N);
    heads_k<<<BG, 256, 0, stream>>>(msum, mkey, cnt, chW1, chb1, chW2, chb2, chW3, chb3,
                                    tW1, tb1, tW2, tb2, dW1, db1, dW2, db2,
                                    out + (size_t)N * MC,
                                    out + (size_t)N * MC + BG * MC,
                                    out + (size_t)N * MC + BG * MC + BG * NT);
}

// Round 5
// 904.264 us; speedup vs baseline: 1.2394x; 1.2394x over previous
//
#include <hip/hip_runtime.h>
#include <hip/hip_bf16.h>

constexpr int DIN = 16;
constexpr int D   = 256;
constexpr int NH  = 8;
constexpr int NC  = 32;
constexpr int MC  = 200;
constexpr int NT  = 8;
constexpr int BG  = 16;
constexpr int NL  = 6;
constexpr float NEG = 0.2f;

// block-wide (256-thread) sum, LDS tree, result broadcast to all threads.
__device__ inline float blocksum256(float v, float* rbuf, int t) {
    __syncthreads();
    rbuf[t] = v;
    __syncthreads();
    if (t < 128) rbuf[t] += rbuf[t + 128]; __syncthreads();
    if (t < 64)  rbuf[t] += rbuf[t + 64];  __syncthreads();
    if (t < 32)  rbuf[t] += rbuf[t + 32];  __syncthreads();
    if (t < 16)  rbuf[t] += rbuf[t + 16];  __syncthreads();
    if (t < 8)   rbuf[t] += rbuf[t + 8];   __syncthreads();
    if (t < 4)   rbuf[t] += rbuf[t + 4];   __syncthreads();
    if (t < 2)   rbuf[t] += rbuf[t + 2];   __syncthreads();
    if (t < 1)   rbuf[t] += rbuf[t + 1];   __syncthreads();
    float r = rbuf[0];
    __syncthreads();
    return r;
}

// ---------------------------------------------------------------- init (deg only; pool no longer needs zeroed buffers)
__global__ __launch_bounds__(256) void init_k(int* __restrict__ deg, int N) {
    int i = blockIdx.x * 256 + threadIdx.x;
    if (i < N) deg[i] = 1;                 // self-loop pre-counted
}

// ---------------------------------------------------------------- encoder: h = relu(LN(x@W+b))
__global__ __launch_bounds__(256) void enc_k(const float* __restrict__ x, const float* __restrict__ W,
                                             const float* __restrict__ b, const float* __restrict__ ls,
                                             const float* __restrict__ lb, float* __restrict__ h, int N) {
    int n = blockIdx.x, t = threadIdx.x;
    __shared__ float xs[DIN];
    __shared__ float rbuf[256];
    if (t < DIN) xs[t] = x[n * DIN + t];
    __syncthreads();
    float acc = b[t];
#pragma unroll
    for (int k = 0; k < DIN; k++) acc = fmaf(xs[k], W[k * D + t], acc);
    float mu = blocksum256(acc, rbuf, t) * (1.f / D);
    float d = acc - mu;
    float var = blocksum256(d * d, rbuf, t) * (1.f / D);
    float rstd = rsqrtf(var + 1e-5f);
    float y = d * rstd * ls[t] + lb[t];
    h[(size_t)n * D + t] = fmaxf(y, 0.f);
}

// ---------------------------------------------------------------- CSR build
__global__ __launch_bounds__(256) void count_k(const int* __restrict__ dst, int* __restrict__ deg, int E) {
    int e = blockIdx.x * 256 + threadIdx.x;
    if (e < E) atomicAdd(&deg[dst[e]], 1);
}

__global__ __launch_bounds__(1024) void scan_k(const int* __restrict__ deg, int* __restrict__ row_ptr,
                                               int* __restrict__ fill, int N) {
    __shared__ int sd[1024];
    int t = threadIdx.x;
    int chunk = (N + 1023) >> 10;
    int lo = t * chunk, hi = min(lo + chunk, N);
    int s = 0;
    for (int i = lo; i < hi; i++) s += deg[i];
    sd[t] = s;
    __syncthreads();
    for (int off = 1; off < 1024; off <<= 1) {
        int v = (t >= off) ? sd[t - off] : 0;
        __syncthreads();
        sd[t] += v;
        __syncthreads();
    }
    int run = (t > 0) ? sd[t - 1] : 0;
    for (int i = lo; i < hi; i++) {
        row_ptr[i] = run; fill[i] = run;
        run += deg[i];
    }
    if (t == 1023) row_ptr[N] = sd[1023];
}

__global__ __launch_bounds__(256) void scatter_k(const int* __restrict__ src, const int* __restrict__ dst,
                                                 int* __restrict__ fill, int* __restrict__ col, int E, int N) {
    int e = blockIdx.x * 256 + threadIdx.x;
    if (e < E) {
        int p = atomicAdd(&fill[dst[e]], 1);
        col[p] = src[e];
    } else if (e < E + N) {
        int n = e - E;
        int p = atomicAdd(&fill[n], 1);
        col[p] = n;                       // self loop
    }
}

// ---------------------------------------------------------------- xl = h@Wl+bl, xr = h@Wr+br  (16 nodes/block)
__global__ __launch_bounds__(256) void gemm_lr_k(const float* __restrict__ h,
                                                 const float* __restrict__ Wl, const float* __restrict__ bl,
                                                 const float* __restrict__ Wr, const float* __restrict__ br,
                                                 float* __restrict__ xl, float* __restrict__ xr, int N) {
    int t = threadIdx.x;
    int nb = blockIdx.x * 16;
    int nmax = min(16, N - nb);
    __shared__ float hs[16][D];
#pragma unroll
    for (int r = 0; r < 16; r++) hs[r][t] = (r < nmax) ? h[(size_t)(nb + r) * D + t] : 0.f;
    __syncthreads();
    float accl[16], accr[16];
    float blv = bl[t], brv = br[t];
#pragma unroll
    for (int r = 0; r < 16; r++) { accl[r] = blv; accr[r] = brv; }
    for (int k = 0; k < D; k += 4) {
        float wl0 = Wl[(k + 0) * D + t], wr0 = Wr[(k + 0) * D + t];
        float wl1 = Wl[(k + 1) * D + t], wr1 = Wr[(k + 1) * D + t];
        float wl2 = Wl[(k + 2) * D + t], wr2 = Wr[(k + 2) * D + t];
        float wl3 = Wl[(k + 3) * D + t], wr3 = Wr[(k + 3) * D + t];
#pragma unroll
        for (int r = 0; r < 16; r++) {
            float4 hv = *(const float4*)&hs[r][k];   // LDS b128 broadcast
            accl[r] = fmaf(hv.x, wl0, accl[r]); accr[r] = fmaf(hv.x, wr0, accr[r]);
            accl[r] = fmaf(hv.y, wl1, accl[r]); accr[r] = fmaf(hv.y, wr1, accr[r]);
            accl[r] = fmaf(hv.z, wl2, accl[r]); accr[r] = fmaf(hv.z, wr2, accr[r]);
            accl[r] = fmaf(hv.w, wl3, accl[r]); accr[r] = fmaf(hv.w, wr3, accr[r]);
        }
    }
    for (int r = 0; r < nmax; r++) {
        xl[(size_t)(nb + r) * D + t] = accl[r];
        xr[(size_t)(nb + r) * D + t] = accr[r];
    }
}

// ---------------------------------------------------------------- fused GATv2: ONE WAVE per dst node.
// lane L holds channels [4L,4L+3]; head of lane group = L/8 (8 lanes * 4 ch = 32 ch/head).
// Per-head dot via 3 shuffles (masks 1,2,4 stay inside the 8-lane group). No LDS, no barriers.
__global__ __launch_bounds__(256) void attn_k(const float* __restrict__ xl, const float* __restrict__ xr,
                                              const int* __restrict__ row_ptr, const int* __restrict__ col,
                                              const float* __restrict__ att, const float* __restrict__ gb,
                                              const float* __restrict__ gls, const float* __restrict__ glb,
                                              float* __restrict__ h, int layer, int N) {
    int t = threadIdx.x;
    int lane = t & 63;
    int n = blockIdx.x * 4 + (t >> 6);
    if (n >= N) return;
    int c4 = lane * 4;
    float4 xrv = *(const float4*)&xr[(size_t)n * D + c4];
    float4 av  = *(const float4*)&att[c4];
    int beg = row_ptr[n], end = row_ptr[n + 1];
    float m = -3.0e38f, l = 0.f;
    float4 acc = make_float4(0.f, 0.f, 0.f, 0.f);
    int src = col[beg];
    float4 xlv = *(const float4*)&xl[(size_t)src * D + c4];
    for (int e = beg; e < end; e++) {
        // prefetch next edge's xl while computing current
        float4 nxt;
        if (e + 1 < end) {
            int nsrc = col[e + 1];
            nxt = *(const float4*)&xl[(size_t)nsrc * D + c4];
        }
        float sx = xlv.x + xrv.x; sx = sx > 0.f ? sx : NEG * sx;
        float sy = xlv.y + xrv.y; sy = sy > 0.f ? sy : NEG * sy;
        float sz = xlv.z + xrv.z; sz = sz > 0.f ? sz : NEG * sz;
        float sw = xlv.w + xrv.w; sw = sw > 0.f ? sw : NEG * sw;
        float z = av.x * sx + av.y * sy + av.z * sz + av.w * sw;
        z += __shfl_xor(z, 1); z += __shfl_xor(z, 2); z += __shfl_xor(z, 4);
        float mn = fmaxf(m, z);
        float sc = __expf(m - mn);
        float p  = __expf(z - mn);
        l = l * sc + p;
        acc.x = acc.x * sc + p * xlv.x;
        acc.y = acc.y * sc + p * xlv.y;
        acc.z = acc.z * sc + p * xlv.z;
        acc.w = acc.w * sc + p * xlv.w;
        m = mn;
        xlv = nxt;
    }
    float4 gbv  = *(const float4*)&gb[c4];
    float rl = 1.f / l;
    float4 o = make_float4(acc.x * rl + gbv.x, acc.y * rl + gbv.y,
                           acc.z * rl + gbv.z, acc.w * rl + gbv.w);
    // LayerNorm over 256 channels spread across the wave: 6-step butterfly
    float s = o.x + o.y + o.z + o.w;
#pragma unroll
    for (int msk = 1; msk <= 32; msk <<= 1) s += __shfl_xor(s, msk);
    float mu = s * (1.f / D);
    float4 dv = make_float4(o.x - mu, o.y - mu, o.z - mu, o.w - mu);
    float v2 = dv.x * dv.x + dv.y * dv.y + dv.z * dv.z + dv.w * dv.w;
#pragma unroll
    for (int msk = 1; msk <= 32; msk <<= 1) v2 += __shfl_xor(v2, msk);
    float rstd = rsqrtf(v2 * (1.f / D) + 1e-5f);
    float4 glsv = *(const float4*)&gls[c4];
    float4 glbv = *(const float4*)&glb[c4];
    float y0 = dv.x * rstd * glsv.x + glbv.x;
    float y1 = dv.y * rstd * glsv.y + glbv.y;
    float y2 = dv.z * rstd * glsv.z + glbv.z;
    float y3 = dv.w * rstd * glsv.w + glbv.w;
    y0 = y0 > 0.f ? y0 : expm1f(y0);
    y1 = y1 > 0.f ? y1 : expm1f(y1);
    y2 = y2 > 0.f ? y2 : expm1f(y2);
    y3 = y3 > 0.f ? y3 : expm1f(y3);
    float4 prev = make_float4(0.f, 0.f, 0.f, 0.f);
    if (layer > 0) prev = *(const float4*)&h[(size_t)n * D + c4];
    float4 res = make_float4(prev.x + y0, prev.y + y1, prev.z + y2, prev.w + y3);
    *(float4*)&h[(size_t)n * D + c4] = res;
}

// ---------------------------------------------------------------- per-node color head MLP (16 nodes/block)
__global__ __launch_bounds__(256) void color_k(const float* __restrict__ h,
                                               const float* __restrict__ W1, const float* __restrict__ b1,
                                               const float* __restrict__ W2, const float* __restrict__ b2,
                                               const float* __restrict__ W3, const float* __restrict__ b3,
                                               float* __restrict__ out, int N) {
    int t = threadIdx.x;
    int nb = blockIdx.x * 16;
    int nmax = min(16, N - nb);
    __shared__ float hs[16][D];
    __shared__ float z1[16][D];
    __shared__ float z2[16][128];
#pragma unroll
    for (int r = 0; r < 16; r++) hs[r][t] = (r < nmax) ? h[(size_t)(nb + r) * D + t] : 0.f;
    __syncthreads();
    float a[16];
    {
        float bv = b1[t];
#pragma unroll
        for (int r = 0; r < 16; r++) a[r] = bv;
        for (int k = 0; k < D; k += 4) {
            float w0 = W1[(k + 0) * D + t];
            float w1 = W1[(k + 1) * D + t];
            float w2 = W1[(k + 2) * D + t];
            float w3 = W1[(k + 3) * D + t];
#pragma unroll
            for (int r = 0; r < 16; r++) {
                float4 hv = *(const float4*)&hs[r][k];
                a[r] = fmaf(hv.x, w0, a[r]);
                a[r] = fmaf(hv.y, w1, a[r]);
                a[r] = fmaf(hv.z, w2, a[r]);
                a[r] = fmaf(hv.w, w3, a[r]);
            }
        }
#pragma unroll
        for (int r = 0; r < 16; r++) z1[r][t] = fmaxf(a[r], 0.f);
    }
    __syncthreads();
    if (t < 128) {
        float bv = b2[t];
#pragma unroll
        for (int r = 0; r < 16; r++) a[r] = bv;
        for (int k = 0; k < D; k += 4) {
            float w0 = W2[(k + 0) * 128 + t];
            float w1 = W2[(k + 1) * 128 + t];
            float w2 = W2[(k + 2) * 128 + t];
            float w3 = W2[(k + 3) * 128 + t];
#pragma unroll
            for (int r = 0; r < 16; r++) {
                float4 zv = *(const float4*)&z1[r][k];
                a[r] = fmaf(zv.x, w0, a[r]);
                a[r] = fmaf(zv.y, w1, a[r]);
                a[r] = fmaf(zv.z, w2, a[r]);
                a[r] = fmaf(zv.w, w3, a[r]);
            }
        }
#pragma unroll
        for (int r = 0; r < 16; r++) z2[r][t] = fmaxf(a[r], 0.f);
    }
    __syncthreads();
    if (t < MC) {
        float bv = b3[t];
#pragma unroll
        for (int r = 0; r < 16; r++) a[r] = bv;
        for (int k = 0; k < 128; k += 4) {
            float w0 = W3[(k + 0) * MC + t];
            float w1 = W3[(k + 1) * MC + t];
            float w2 = W3[(k + 2) * MC + t];
            float w3 = W3[(k + 3) * MC + t];
#pragma unroll
            for (int r = 0; r < 16; r++) {
                float4 zv = *(const float4*)&z2[r][k];
                a[r] = fmaf(zv.x, w0, a[r]);
                a[r] = fmaf(zv.y, w1, a[r]);
                a[r] = fmaf(zv.z, w2, a[r]);
                a[r] = fmaf(zv.w, w3, a[r]);
            }
        }
        for (int r = 0; r < nmax; r++) out[(size_t)(nb + r) * MC + t] = a[r];
    }
}

// ---------------------------------------------------------------- pooling: batch is SORTED -> block
// (graph b, channel chunk) binary-searches its node range; register reduction; zero atomics.
__global__ __launch_bounds__(64) void pool_k(const float* __restrict__ h, const int* __restrict__ batch,
                                             float* __restrict__ msum, float* __restrict__ mmax,
                                             int* __restrict__ cnt, int N) {
    int b = blockIdx.x;
    int c = blockIdx.y * 64 + threadIdx.x;
    int lo = 0, hi = N;
    while (lo < hi) { int mid = (lo + hi) >> 1; if (batch[mid] < b) lo = mid + 1; else hi = mid; }
    int s0 = lo;
    lo = 0; hi = N;
    while (lo < hi) { int mid = (lo + hi) >> 1; if (batch[mid] < b + 1) lo = mid + 1; else hi = mid; }
    int s1 = lo;
    float sum = 0.f, mx = -3.0e38f;
    for (int n = s0; n < s1; n++) {
        float v = h[(size_t)n * D + c];
        sum += v;
        mx = fmaxf(mx, v);
    }
    msum[b * D + c] = sum;
    mmax[b * D + c] = (s1 > s0) ? mx : 0.f;
    if (c == 0) cnt[b] = s1 - s0;
}

// ---------------------------------------------------------------- graph heads (one block per graph)
__global__ __launch_bounds__(256) void heads_k(const float* __restrict__ msum, const float* __restrict__ mmax,
                                               const int* __restrict__ cnt,
                                               const float* __restrict__ chW1, const float* __restrict__ chb1,
                                               const float* __restrict__ chW2, const float* __restrict__ chb2,
                                               const float* __restrict__ chW3, const float* __restrict__ chb3,
                                               const float* __restrict__ tW1, const float* __restrict__ tb1,
                                               const float* __restrict__ tW2, const float* __restrict__ tb2,
                                               const float* __restrict__ dW1, const float* __restrict__ db1,
                                               const float* __restrict__ dW2, const float* __restrict__ db2,
                                               float* __restrict__ out_ch, float* __restrict__ out_t,
                                               float* __restrict__ out_d) {
    int b = blockIdx.x, t = threadIdx.x;
    __shared__ float g[2 * D];
    __shared__ float z1[D];
    __shared__ float z2[128];
    float c = fmaxf((float)cnt[b], 1.f);
    g[t] = msum[b * D + t] / c;
    g[D + t] = mmax[b * D + t];
    __syncthreads();
    // chromatic head: 512 -> 256 -> 128 -> MC
    float a = chb1[t];
    for (int k = 0; k < 2 * D; k++) a = fmaf(g[k], chW1[k * D + t], a);
    z1[t] = fmaxf(a, 0.f);
    __syncthreads();
    if (t < 128) {
        a = chb2[t];
        for (int k = 0; k < D; k++) a = fmaf(z1[k], chW2[k * 128 + t], a);
        z2[t] = fmaxf(a, 0.f);
    }
    __syncthreads();
    if (t < MC) {
        a = chb3[t];
        for (int k = 0; k < 128; k++) a = fmaf(z2[k], chW3[k * MC + t], a);
        out_ch[b * MC + t] = a;
    }
    __syncthreads();
    // type head: 512 -> 128 -> NT
    if (t < 128) {
        a = tb1[t];
        for (int k = 0; k < 2 * D; k++) a = fmaf(g[k], tW1[k * 128 + t], a);
        z1[t] = fmaxf(a, 0.f);
    }
    __syncthreads();
    if (t < NT) {
        a = tb2[t];
        for (int k = 0; k < 128; k++) a = fmaf(z1[k], tW2[k * NT + t], a);
        out_t[b * NT + t] = a;
    }
    __syncthreads();
    // difficulty head: 512 -> 64 -> 1, sigmoid*100
    if (t < 64) {
        a = db1[t];
        for (int k = 0; k < 2 * D; k++) a = fmaf(g[k], dW1[k * 64 + t], a);
        z1[t] = fmaxf(a, 0.f);
    }
    __syncthreads();
    if (t == 0) {
        a = db2[0];
        for (int k = 0; k < 64; k++) a = fmaf(z1[k], dW2[k], a);
        float sg = 1.f / (1.f + __expf(-a));
        out_d[b] = 100.f * sg;
    }
}

// ----------------------------------------------------------------
extern "C" void kernel_launch(void* const* d_in, const int* in_sizes, int n_in,
                              void* d_out, int out_size, void* d_ws, size_t ws_size,
                              hipStream_t stream) {
    const float* x     = (const float*)d_in[0];
    const int*   ei    = (const int*)d_in[1];
    const int*   batch = (const int*)d_in[2];
    const float* encW  = (const float*)d_in[3];
    const float* encb  = (const float*)d_in[4];
    const float* encls = (const float*)d_in[5];
    const float* enclb = (const float*)d_in[6];
    const float* Wl    = (const float*)d_in[7];
    const float* bl    = (const float*)d_in[8];
    const float* Wr    = (const float*)d_in[9];
    const float* br    = (const float*)d_in[10];
    const float* att   = (const float*)d_in[11];
    const float* gb    = (const float*)d_in[12];
    const float* gls   = (const float*)d_in[13];
    const float* glb   = (const float*)d_in[14];
    const float* cW1   = (const float*)d_in[15];
    const float* cb1   = (const float*)d_in[16];
    const float* cW2   = (const float*)d_in[17];
    const float* cb2   = (const float*)d_in[18];
    const float* cW3   = (const float*)d_in[19];
    const float* cb3   = (const float*)d_in[20];
    const float* chW1  = (const float*)d_in[21];
    const float* chb1  = (const float*)d_in[22];
    const float* chW2  = (const float*)d_in[23];
    const float* chb2  = (const float*)d_in[24];
    const float* chW3  = (const float*)d_in[25];
    const float* chb3  = (const float*)d_in[26];
    const float* tW1   = (const float*)d_in[27];
    const float* tb1   = (const float*)d_in[28];
    const float* tW2   = (const float*)d_in[29];
    const float* tb2   = (const float*)d_in[30];
    const float* dW1   = (const float*)d_in[31];
    const float* db1   = (const float*)d_in[32];
    const float* dW2   = (const float*)d_in[33];
    const float* db2   = (const float*)d_in[34];

    const int N = in_sizes[0] / DIN;
    const int E = in_sizes[1] / 2;
    const int* esrc = ei;
    const int* edst = ei + E;

    char* p = (char*)d_ws;
    auto carve = [&](size_t bytes) { char* r = p; p += (bytes + 255) & ~(size_t)255; return r; };
    int*      row_ptr = (int*)carve((size_t)(N + 1) * 4);
    int*      fill    = (int*)carve((size_t)N * 4);
    int*      deg     = (int*)carve((size_t)N * 4);
    int*      cnt     = (int*)carve((size_t)BG * 4);
    float*    msum    = (float*)carve((size_t)BG * D * 4);
    float*    mmax    = (float*)carve((size_t)BG * D * 4);
    int*      col     = (int*)carve((size_t)(E + N) * 4);
    float*    h       = (float*)carve((size_t)N * D * 4);
    float*    xl      = (float*)carve((size_t)N * D * 4);
    float*    xr      = (float*)carve((size_t)N * D * 4);
    (void)ws_size; (void)n_in; (void)out_size;

    init_k<<<(N + 255) / 256, 256, 0, stream>>>(deg, N);
    enc_k<<<N, 256, 0, stream>>>(x, encW, encb, encls, enclb, h, N);
    count_k<<<(E + 255) / 256, 256, 0, stream>>>(edst, deg, E);
    scan_k<<<1, 1024, 0, stream>>>(deg, row_ptr, fill, N);
    scatter_k<<<(E + N + 255) / 256, 256, 0, stream>>>(esrc, edst, fill, col, E, N);

    for (int i = 0; i < NL; i++) {
        gemm_lr_k<<<(N + 15) / 16, 256, 0, stream>>>(h, Wl + (size_t)i * D * D, bl + i * D,
                                                     Wr + (size_t)i * D * D, br + i * D, xl, xr, N);
        attn_k<<<(N + 3) / 4, 256, 0, stream>>>(xl, xr, row_ptr, col, att + i * NH * NC,
                                                gb + i * D, gls + i * D, glb + i * D, h, i, N);
    }

    float* out = (float*)d_out;
    color_k<<<(N + 15) / 16, 256, 0, stream>>>(h, cW1, cb1, cW2, cb2, cW3, cb3, out, N);
    pool_k<<<dim3(BG, 4), 64, 0, stream>>>(h, batch, msum, mmax, cnt, N);
    heads_k<<<BG, 256, 0, stream>>>(msum, mmax, cnt, chW1, chb1, chW2, chb2, chW3, chb3,
                                    tW1, tb1, tW2, tb2, dW1, db1, dW2, db2,
                                    out + (size_t)N * MC,
                                    out + (size_t)N * MC + BG * MC,
                                    out + (size_t)N * MC + BG * MC + BG * NT);
}

// Round 6
// 793.625 us; speedup vs baseline: 1.4121x; 1.1394x over previous
//
#include <hip/hip_runtime.h>
#include <hip/hip_bf16.h>

constexpr int DIN = 16;
constexpr int D   = 256;
constexpr int NH  = 8;
constexpr int NC  = 32;
constexpr int MC  = 200;
constexpr int NT  = 8;
constexpr int BG  = 16;
constexpr int NL  = 6;
constexpr int PS  = 16;   // pool slices per graph
constexpr float NEG = 0.2f;

// block-wide (256-thread) sum, LDS tree, result broadcast to all threads.
__device__ inline float blocksum256(float v, float* rbuf, int t) {
    __syncthreads();
    rbuf[t] = v;
    __syncthreads();
    if (t < 128) rbuf[t] += rbuf[t + 128]; __syncthreads();
    if (t < 64)  rbuf[t] += rbuf[t + 64];  __syncthreads();
    if (t < 32)  rbuf[t] += rbuf[t + 32];  __syncthreads();
    if (t < 16)  rbuf[t] += rbuf[t + 16];  __syncthreads();
    if (t < 8)   rbuf[t] += rbuf[t + 8];   __syncthreads();
    if (t < 4)   rbuf[t] += rbuf[t + 4];   __syncthreads();
    if (t < 2)   rbuf[t] += rbuf[t + 2];   __syncthreads();
    if (t < 1)   rbuf[t] += rbuf[t + 1];   __syncthreads();
    float r = rbuf[0];
    __syncthreads();
    return r;
}

// ---------------------------------------------------------------- init
__global__ __launch_bounds__(256) void init_k(int* __restrict__ deg, int N) {
    int i = blockIdx.x * 256 + threadIdx.x;
    if (i < N) deg[i] = 1;                 // self-loop pre-counted
}

// ---------------------------------------------------------------- encoder: h = relu(LN(x@W+b))
__global__ __launch_bounds__(256) void enc_k(const float* __restrict__ x, const float* __restrict__ W,
                                             const float* __restrict__ b, const float* __restrict__ ls,
                                             const float* __restrict__ lb, float* __restrict__ h, int N) {
    int n = blockIdx.x, t = threadIdx.x;
    __shared__ float xs[DIN];
    __shared__ float rbuf[256];
    if (t < DIN) xs[t] = x[n * DIN + t];
    __syncthreads();
    float acc = b[t];
#pragma unroll
    for (int k = 0; k < DIN; k++) acc = fmaf(xs[k], W[k * D + t], acc);
    float mu = blocksum256(acc, rbuf, t) * (1.f / D);
    float d = acc - mu;
    float var = blocksum256(d * d, rbuf, t) * (1.f / D);
    float rstd = rsqrtf(var + 1e-5f);
    float y = d * rstd * ls[t] + lb[t];
    h[(size_t)n * D + t] = fmaxf(y, 0.f);
}

// ---------------------------------------------------------------- CSR build
__global__ __launch_bounds__(256) void count_k(const int* __restrict__ dst, int* __restrict__ deg, int E) {
    int e = blockIdx.x * 256 + threadIdx.x;
    if (e < E) atomicAdd(&deg[dst[e]], 1);
}

__global__ __launch_bounds__(1024) void scan_k(const int* __restrict__ deg, int* __restrict__ row_ptr,
                                               int* __restrict__ fill, int N) {
    __shared__ int sd[1024];
    int t = threadIdx.x;
    int chunk = (N + 1023) >> 10;
    int lo = t * chunk, hi = min(lo + chunk, N);
    int s = 0;
    for (int i = lo; i < hi; i++) s += deg[i];
    sd[t] = s;
    __syncthreads();
    for (int off = 1; off < 1024; off <<= 1) {
        int v = (t >= off) ? sd[t - off] : 0;
        __syncthreads();
        sd[t] += v;
        __syncthreads();
    }
    int run = (t > 0) ? sd[t - 1] : 0;
    for (int i = lo; i < hi; i++) {
        row_ptr[i] = run; fill[i] = run;
        run += deg[i];
    }
    if (t == 1023) row_ptr[N] = sd[1023];
}

__global__ __launch_bounds__(256) void scatter_k(const int* __restrict__ src, const int* __restrict__ dst,
                                                 int* __restrict__ fill, int* __restrict__ col, int E, int N) {
    int e = blockIdx.x * 256 + threadIdx.x;
    if (e < E) {
        int p = atomicAdd(&fill[dst[e]], 1);
        col[p] = src[e];
    } else if (e < E + N) {
        int n = e - E;
        int p = atomicAdd(&fill[n], 1);
        col[p] = n;                       // self loop
    }
}

// ---------------------------------------------------------------- xl = h@Wl+bl, xr = h@Wr+br  (16 nodes/block)
// NOTE: all register-array indexing must be compile-time (predicated unroll), else scratch spill.
__global__ __launch_bounds__(256) void gemm_lr_k(const float* __restrict__ h,
                                                 const float* __restrict__ Wl, const float* __restrict__ bl,
                                                 const float* __restrict__ Wr, const float* __restrict__ br,
                                                 float* __restrict__ xl, float* __restrict__ xr, int N) {
    int t = threadIdx.x;
    int nb = blockIdx.x * 16;
    int nmax = min(16, N - nb);
    __shared__ float hs[16][D];
#pragma unroll
    for (int r = 0; r < 16; r++) hs[r][t] = (r < nmax) ? h[(size_t)(nb + r) * D + t] : 0.f;
    __syncthreads();
    float accl[16], accr[16];
    float blv = bl[t], brv = br[t];
#pragma unroll
    for (int r = 0; r < 16; r++) { accl[r] = blv; accr[r] = brv; }
    for (int k = 0; k < D; k += 4) {
        float wl0 = Wl[(k + 0) * D + t], wr0 = Wr[(k + 0) * D + t];
        float wl1 = Wl[(k + 1) * D + t], wr1 = Wr[(k + 1) * D + t];
        float wl2 = Wl[(k + 2) * D + t], wr2 = Wr[(k + 2) * D + t];
        float wl3 = Wl[(k + 3) * D + t], wr3 = Wr[(k + 3) * D + t];
#pragma unroll
        for (int r = 0; r < 16; r++) {
            float4 hv = *(const float4*)&hs[r][k];   // LDS b128 broadcast
            accl[r] = fmaf(hv.x, wl0, accl[r]); accr[r] = fmaf(hv.x, wr0, accr[r]);
            accl[r] = fmaf(hv.y, wl1, accl[r]); accr[r] = fmaf(hv.y, wr1, accr[r]);
            accl[r] = fmaf(hv.z, wl2, accl[r]); accr[r] = fmaf(hv.z, wr2, accr[r]);
            accl[r] = fmaf(hv.w, wl3, accl[r]); accr[r] = fmaf(hv.w, wr3, accr[r]);
        }
    }
#pragma unroll
    for (int r = 0; r < 16; r++) {
        if (r < nmax) {
            xl[(size_t)(nb + r) * D + t] = accl[r];
            xr[(size_t)(nb + r) * D + t] = accr[r];
        }
    }
}

// ---------------------------------------------------------------- fused GATv2: ONE WAVE per dst node.
__global__ __launch_bounds__(256) void attn_k(const float* __restrict__ xl, const float* __restrict__ xr,
                                              const int* __restrict__ row_ptr, const int* __restrict__ col,
                                              const float* __restrict__ att, const float* __restrict__ gb,
                                              const float* __restrict__ gls, const float* __restrict__ glb,
                                              float* __restrict__ h, int layer, int N) {
    int t = threadIdx.x;
    int lane = t & 63;
    int n = blockIdx.x * 4 + (t >> 6);
    if (n >= N) return;
    int c4 = lane * 4;
    float4 xrv = *(const float4*)&xr[(size_t)n * D + c4];
    float4 av  = *(const float4*)&att[c4];
    int beg = row_ptr[n], end = row_ptr[n + 1];
    float m = -3.0e38f, l = 0.f;
    float4 acc = make_float4(0.f, 0.f, 0.f, 0.f);
    int src = col[beg];
    float4 xlv = *(const float4*)&xl[(size_t)src * D + c4];
    for (int e = beg; e < end; e++) {
        float4 nxt;
        if (e + 1 < end) {
            int nsrc = col[e + 1];
            nxt = *(const float4*)&xl[(size_t)nsrc * D + c4];
        }
        float sx = xlv.x + xrv.x; sx = sx > 0.f ? sx : NEG * sx;
        float sy = xlv.y + xrv.y; sy = sy > 0.f ? sy : NEG * sy;
        float sz = xlv.z + xrv.z; sz = sz > 0.f ? sz : NEG * sz;
        float sw = xlv.w + xrv.w; sw = sw > 0.f ? sw : NEG * sw;
        float z = av.x * sx + av.y * sy + av.z * sz + av.w * sw;
        z += __shfl_xor(z, 1); z += __shfl_xor(z, 2); z += __shfl_xor(z, 4);
        float mn = fmaxf(m, z);
        float sc = __expf(m - mn);
        float p  = __expf(z - mn);
        l = l * sc + p;
        acc.x = acc.x * sc + p * xlv.x;
        acc.y = acc.y * sc + p * xlv.y;
        acc.z = acc.z * sc + p * xlv.z;
        acc.w = acc.w * sc + p * xlv.w;
        m = mn;
        xlv = nxt;
    }
    float4 gbv  = *(const float4*)&gb[c4];
    float rl = 1.f / l;
    float4 o = make_float4(acc.x * rl + gbv.x, acc.y * rl + gbv.y,
                           acc.z * rl + gbv.z, acc.w * rl + gbv.w);
    float s = o.x + o.y + o.z + o.w;
#pragma unroll
    for (int msk = 1; msk <= 32; msk <<= 1) s += __shfl_xor(s, msk);
    float mu = s * (1.f / D);
    float4 dv = make_float4(o.x - mu, o.y - mu, o.z - mu, o.w - mu);
    float v2 = dv.x * dv.x + dv.y * dv.y + dv.z * dv.z + dv.w * dv.w;
#pragma unroll
    for (int msk = 1; msk <= 32; msk <<= 1) v2 += __shfl_xor(v2, msk);
    float rstd = rsqrtf(v2 * (1.f / D) + 1e-5f);
    float4 glsv = *(const float4*)&gls[c4];
    float4 glbv = *(const float4*)&glb[c4];
    float y0 = dv.x * rstd * glsv.x + glbv.x;
    float y1 = dv.y * rstd * glsv.y + glbv.y;
    float y2 = dv.z * rstd * glsv.z + glbv.z;
    float y3 = dv.w * rstd * glsv.w + glbv.w;
    y0 = y0 > 0.f ? y0 : expm1f(y0);
    y1 = y1 > 0.f ? y1 : expm1f(y1);
    y2 = y2 > 0.f ? y2 : expm1f(y2);
    y3 = y3 > 0.f ? y3 : expm1f(y3);
    float4 prev = make_float4(0.f, 0.f, 0.f, 0.f);
    if (layer > 0) prev = *(const float4*)&h[(size_t)n * D + c4];
    float4 res = make_float4(prev.x + y0, prev.y + y1, prev.z + y2, prev.w + y3);
    *(float4*)&h[(size_t)n * D + c4] = res;
}

// ---------------------------------------------------------------- per-node color head MLP (16 nodes/block)
__global__ __launch_bounds__(256) void color_k(const float* __restrict__ h,
                                               const float* __restrict__ W1, const float* __restrict__ b1,
                                               const float* __restrict__ W2, const float* __restrict__ b2,
                                               const float* __restrict__ W3, const float* __restrict__ b3,
                                               float* __restrict__ out, int N) {
    int t = threadIdx.x;
    int nb = blockIdx.x * 16;
    int nmax = min(16, N - nb);
    __shared__ float hs[16][D];
    __shared__ float z1[16][D];
    __shared__ float z2[16][128];
#pragma unroll
    for (int r = 0; r < 16; r++) hs[r][t] = (r < nmax) ? h[(size_t)(nb + r) * D + t] : 0.f;
    __syncthreads();
    float a[16];
    {
        float bv = b1[t];
#pragma unroll
        for (int r = 0; r < 16; r++) a[r] = bv;
        for (int k = 0; k < D; k += 4) {
            float w0 = W1[(k + 0) * D + t];
            float w1 = W1[(k + 1) * D + t];
            float w2 = W1[(k + 2) * D + t];
            float w3 = W1[(k + 3) * D + t];
#pragma unroll
            for (int r = 0; r < 16; r++) {
                float4 hv = *(const float4*)&hs[r][k];
                a[r] = fmaf(hv.x, w0, a[r]);
                a[r] = fmaf(hv.y, w1, a[r]);
                a[r] = fmaf(hv.z, w2, a[r]);
                a[r] = fmaf(hv.w, w3, a[r]);
            }
        }
#pragma unroll
        for (int r = 0; r < 16; r++) z1[r][t] = fmaxf(a[r], 0.f);
    }
    __syncthreads();
    if (t < 128) {
        float bv = b2[t];
#pragma unroll
        for (int r = 0; r < 16; r++) a[r] = bv;
        for (int k = 0; k < D; k += 4) {
            float w0 = W2[(k + 0) * 128 + t];
            float w1 = W2[(k + 1) * 128 + t];
            float w2 = W2[(k + 2) * 128 + t];
            float w3 = W2[(k + 3) * 128 + t];
#pragma unroll
            for (int r = 0; r < 16; r++) {
                float4 zv = *(const float4*)&z1[r][k];
                a[r] = fmaf(zv.x, w0, a[r]);
                a[r] = fmaf(zv.y, w1, a[r]);
                a[r] = fmaf(zv.z, w2, a[r]);
                a[r] = fmaf(zv.w, w3, a[r]);
            }
        }
#pragma unroll
        for (int r = 0; r < 16; r++) z2[r][t] = fmaxf(a[r], 0.f);
    }
    __syncthreads();
    if (t < MC) {
        float bv = b3[t];
#pragma unroll
        for (int r = 0; r < 16; r++) a[r] = bv;
        for (int k = 0; k < 128; k += 4) {
            float w0 = W3[(k + 0) * MC + t];
            float w1 = W3[(k + 1) * MC + t];
            float w2 = W3[(k + 2) * MC + t];
            float w3 = W3[(k + 3) * MC + t];
#pragma unroll
            for (int r = 0; r < 16; r++) {
                float4 zv = *(const float4*)&z2[r][k];
                a[r] = fmaf(zv.x, w0, a[r]);
                a[r] = fmaf(zv.y, w1, a[r]);
                a[r] = fmaf(zv.z, w2, a[r]);
                a[r] = fmaf(zv.w, w3, a[r]);
            }
        }
#pragma unroll
        for (int r = 0; r < 16; r++) {
            if (r < nmax) out[(size_t)(nb + r) * MC + t] = a[r];
        }
    }
}

// ---------------------------------------------------------------- pooling stage 1: block (graph b, slice s)
// reduces ~len/PS nodes over 256 channels; partials to ws. Zero atomics, 256x parallelism of round-5.
__global__ __launch_bounds__(256) void pool_k(const float* __restrict__ h, const int* __restrict__ batch,
                                              float* __restrict__ psum, float* __restrict__ pmax,
                                              int* __restrict__ cnt, int N) {
    int b = blockIdx.x;
    int sl = blockIdx.y;
    int c = threadIdx.x;
    int lo = 0, hi = N;
    while (lo < hi) { int mid = (lo + hi) >> 1; if (batch[mid] < b) lo = mid + 1; else hi = mid; }
    int s0 = lo;
    lo = 0; hi = N;
    while (lo < hi) { int mid = (lo + hi) >> 1; if (batch[mid] < b + 1) lo = mid + 1; else hi = mid; }
    int s1 = lo;
    int len = s1 - s0;
    int chunk = (len + PS - 1) / PS;
    int n0 = s0 + sl * chunk;
    int n1 = min(n0 + chunk, s1);
    float sum = 0.f, mx = -3.0e38f;
    for (int n = n0; n < n1; n++) {
        float v = h[(size_t)n * D + c];
        sum += v;
        mx = fmaxf(mx, v);
    }
    psum[(size_t)(b * PS + sl) * D + c] = sum;
    pmax[(size_t)(b * PS + sl) * D + c] = mx;      // -3e38 for empty slices; folded by max
    if (c == 0 && sl == 0) cnt[b] = len;
}

// ---------------------------------------------------------------- graph heads (one block per graph)
__global__ __launch_bounds__(256) void heads_k(const float* __restrict__ psum, const float* __restrict__ pmax,
                                               const int* __restrict__ cnt,
                                               const float* __restrict__ chW1, const float* __restrict__ chb1,
                                               const float* __restrict__ chW2, const float* __restrict__ chb2,
                                               const float* __restrict__ chW3, const float* __restrict__ chb3,
                                               const float* __restrict__ tW1, const float* __restrict__ tb1,
                                               const float* __restrict__ tW2, const float* __restrict__ tb2,
                                               const float* __restrict__ dW1, const float* __restrict__ db1,
                                               const float* __restrict__ dW2, const float* __restrict__ db2,
                                               float* __restrict__ out_ch, float* __restrict__ out_t,
                                               float* __restrict__ out_d) {
    int b = blockIdx.x, t = threadIdx.x;
    __shared__ float g[2 * D];
    __shared__ float z1[D];
    __shared__ float z2[128];
    // fold PS partials
    float sum = 0.f, mx = -3.0e38f;
#pragma unroll
    for (int sl = 0; sl < PS; sl++) {
        sum += psum[(size_t)(b * PS + sl) * D + t];
        mx = fmaxf(mx, pmax[(size_t)(b * PS + sl) * D + t]);
    }
    int cn = cnt[b];
    float c = fmaxf((float)cn, 1.f);
    g[t] = sum / c;
    g[D + t] = (cn > 0) ? mx : 0.f;     // segment_max of empty graph -> where(isfinite,...,0)
    __syncthreads();
    // chromatic head: 512 -> 256 -> 128 -> MC
    float a = chb1[t];
    for (int k = 0; k < 2 * D; k++) a = fmaf(g[k], chW1[k * D + t], a);
    z1[t] = fmaxf(a, 0.f);
    __syncthreads();
    if (t < 128) {
        a = chb2[t];
        for (int k = 0; k < D; k++) a = fmaf(z1[k], chW2[k * 128 + t], a);
        z2[t] = fmaxf(a, 0.f);
    }
    __syncthreads();
    if (t < MC) {
        a = chb3[t];
        for (int k = 0; k < 128; k++) a = fmaf(z2[k], chW3[k * MC + t], a);
        out_ch[b * MC + t] = a;
    }
    __syncthreads();
    // type head: 512 -> 128 -> NT
    if (t < 128) {
        a = tb1[t];
        for (int k = 0; k < 2 * D; k++) a = fmaf(g[k], tW1[k * 128 + t], a);
        z1[t] = fmaxf(a, 0.f);
    }
    __syncthreads();
    if (t < NT) {
        a = tb2[t];
        for (int k = 0; k < 128; k++) a = fmaf(z1[k], tW2[k * NT + t], a);
        out_t[b * NT + t] = a;
    }
    __syncthreads();
    // difficulty head: 512 -> 64 -> 1, sigmoid*100
    if (t < 64) {
        a = db1[t];
        for (int k = 0; k < 2 * D; k++) a = fmaf(g[k], dW1[k * 64 + t], a);
        z1[t] = fmaxf(a, 0.f);
    }
    __syncthreads();
    if (t == 0) {
        a = db2[0];
        for (int k = 0; k < 64; k++) a = fmaf(z1[k], dW2[k], a);
        float sg = 1.f / (1.f + __expf(-a));
        out_d[b] = 100.f * sg;
    }
}

// ----------------------------------------------------------------
extern "C" void kernel_launch(void* const* d_in, const int* in_sizes, int n_in,
                              void* d_out, int out_size, void* d_ws, size_t ws_size,
                              hipStream_t stream) {
    const float* x     = (const float*)d_in[0];
    const int*   ei    = (const int*)d_in[1];
    const int*   batch = (const int*)d_in[2];
    const float* encW  = (const float*)d_in[3];
    const float* encb  = (const float*)d_in[4];
    const float* encls = (const float*)d_in[5];
    const float* enclb = (const float*)d_in[6];
    const float* Wl    = (const float*)d_in[7];
    const float* bl    = (const float*)d_in[8];
    const float* Wr    = (const float*)d_in[9];
    const float* br    = (const float*)d_in[10];
    const float* att   = (const float*)d_in[11];
    const float* gb    = (const float*)d_in[12];
    const float* gls   = (const float*)d_in[13];
    const float* glb   = (const float*)d_in[14];
    const float* cW1   = (const float*)d_in[15];
    const float* cb1   = (const float*)d_in[16];
    const float* cW2   = (const float*)d_in[17];
    const float* cb2   = (const float*)d_in[18];
    const float* cW3   = (const float*)d_in[19];
    const float* cb3   = (const float*)d_in[20];
    const float* chW1  = (const float*)d_in[21];
    const float* chb1  = (const float*)d_in[22];
    const float* chW2  = (const float*)d_in[23];
    const float* chb2  = (const float*)d_in[24];
    const float* chW3  = (const float*)d_in[25];
    const float* chb3  = (const float*)d_in[26];
    const float* tW1   = (const float*)d_in[27];
    const float* tb1   = (const float*)d_in[28];
    const float* tW2   = (const float*)d_in[29];
    const float* tb2   = (const float*)d_in[30];
    const float* dW1   = (const float*)d_in[31];
    const float* db1   = (const float*)d_in[32];
    const float* dW2   = (const float*)d_in[33];
    const float* db2   = (const float*)d_in[34];

    const int N = in_sizes[0] / DIN;
    const int E = in_sizes[1] / 2;
    const int* esrc = ei;
    const int* edst = ei + E;

    char* p = (char*)d_ws;
    auto carve = [&](size_t bytes) { char* r = p; p += (bytes + 255) & ~(size_t)255; return r; };
    int*      row_ptr = (int*)carve((size_t)(N + 1) * 4);
    int*      fill    = (int*)carve((size_t)N * 4);
    int*      deg     = (int*)carve((size_t)N * 4);
    int*      cnt     = (int*)carve((size_t)BG * 4);
    float*    psum    = (float*)carve((size_t)BG * PS * D * 4);
    float*    pmax    = (float*)carve((size_t)BG * PS * D * 4);
    int*      col     = (int*)carve((size_t)(E + N) * 4);
    float*    h       = (float*)carve((size_t)N * D * 4);
    float*    xl      = (float*)carve((size_t)N * D * 4);
    float*    xr      = (float*)carve((size_t)N * D * 4);
    (void)ws_size; (void)n_in; (void)out_size;

    init_k<<<(N + 255) / 256, 256, 0, stream>>>(deg, N);
    enc_k<<<N, 256, 0, stream>>>(x, encW, encb, encls, enclb, h, N);
    count_k<<<(E + 255) / 256, 256, 0, stream>>>(edst, deg, E);
    scan_k<<<1, 1024, 0, stream>>>(deg, row_ptr, fill, N);
    scatter_k<<<(E + N + 255) / 256, 256, 0, stream>>>(esrc, edst, fill, col, E, N);

    for (int i = 0; i < NL; i++) {
        gemm_lr_k<<<(N + 15) / 16, 256, 0, stream>>>(h, Wl + (size_t)i * D * D, bl + i * D,
                                                     Wr + (size_t)i * D * D, br + i * D, xl, xr, N);
        attn_k<<<(N + 3) / 4, 256, 0, stream>>>(xl, xr, row_ptr, col, att + i * NH * NC,
                                                gb + i * D, gls + i * D, glb + i * D, h, i, N);
    }

    float* out = (float*)d_out;
    color_k<<<(N + 15) / 16, 256, 0, stream>>>(h, cW1, cb1, cW2, cb2, cW3, cb3, out, N);
    pool_k<<<dim3(BG, PS), 256, 0, stream>>>(h, batch, psum, pmax, cnt, N);
    heads_k<<<BG, 256, 0, stream>>>(psum, pmax, cnt, chW1, chb1, chW2, chb2, chW3, chb3,
                                    tW1, tb1, tW2, tb2, dW1, db1, dW2, db2,
                                    out + (size_t)N * MC,
                                    out + (size_t)N * MC + BG * MC,
                                    out + (size_t)N * MC + BG * MC + BG * NT);
}

// Round 7
// 549.470 us; speedup vs baseline: 2.0396x; 1.4443x over previous
//
#include <hip/hip_runtime.h>
#include <hip/hip_bf16.h>

constexpr int DIN = 16;
constexpr int D   = 256;
constexpr int NH  = 8;
constexpr int NC  = 32;
constexpr int MC  = 200;
constexpr int NT  = 8;
constexpr int BG  = 16;
constexpr int NL  = 6;
constexpr int PS  = 16;   // pool slices per graph
constexpr float NEG = 0.2f;

typedef __attribute__((ext_vector_type(8))) short bfrag;   // 8 bf16 (4 VGPRs)
typedef __attribute__((ext_vector_type(4))) float f32x4;   // MFMA acc

// fp32 -> bf16 (RNE), bit-level
__device__ inline unsigned short f2bf(float f) {
    unsigned int u = __float_as_uint(f);
    u += 0x7FFFu + ((u >> 16) & 1u);
    return (unsigned short)(u >> 16);
}

// block-wide (256-thread) sum, LDS tree, result broadcast to all threads.
__device__ inline float blocksum256(float v, float* rbuf, int t) {
    __syncthreads();
    rbuf[t] = v;
    __syncthreads();
    if (t < 128) rbuf[t] += rbuf[t + 128]; __syncthreads();
    if (t < 64)  rbuf[t] += rbuf[t + 64];  __syncthreads();
    if (t < 32)  rbuf[t] += rbuf[t + 32];  __syncthreads();
    if (t < 16)  rbuf[t] += rbuf[t + 16];  __syncthreads();
    if (t < 8)   rbuf[t] += rbuf[t + 8];   __syncthreads();
    if (t < 4)   rbuf[t] += rbuf[t + 4];   __syncthreads();
    if (t < 2)   rbuf[t] += rbuf[t + 2];   __syncthreads();
    if (t < 1)   rbuf[t] += rbuf[t + 1];   __syncthreads();
    float r = rbuf[0];
    __syncthreads();
    return r;
}

// ILP-4 dot: out[t] over K terms, weight leading dim ldw
__device__ inline float dot_ilp(const float* __restrict__ g, const float* __restrict__ W,
                                int K, int ldw, int t) {
    float a0 = 0.f, a1 = 0.f, a2 = 0.f, a3 = 0.f;
    for (int k = 0; k < K; k += 4) {
        a0 = fmaf(g[k + 0], W[(k + 0) * ldw + t], a0);
        a1 = fmaf(g[k + 1], W[(k + 1) * ldw + t], a1);
        a2 = fmaf(g[k + 2], W[(k + 2) * ldw + t], a2);
        a3 = fmaf(g[k + 3], W[(k + 3) * ldw + t], a3);
    }
    return (a0 + a1) + (a2 + a3);
}

// ---------------------------------------------------------------- init
__global__ __launch_bounds__(256) void init_k(int* __restrict__ deg, int N) {
    int i = blockIdx.x * 256 + threadIdx.x;
    if (i < N) deg[i] = 1;                 // self-loop pre-counted
}

// ---------------------------------------------------------------- encoder: h = relu(LN(x@W+b))
__global__ __launch_bounds__(256) void enc_k(const float* __restrict__ x, const float* __restrict__ W,
                                             const float* __restrict__ b, const float* __restrict__ ls,
                                             const float* __restrict__ lb, float* __restrict__ h, int N) {
    int n = blockIdx.x, t = threadIdx.x;
    __shared__ float xs[DIN];
    __shared__ float rbuf[256];
    if (t < DIN) xs[t] = x[n * DIN + t];
    __syncthreads();
    float acc = b[t];
#pragma unroll
    for (int k = 0; k < DIN; k++) acc = fmaf(xs[k], W[k * D + t], acc);
    float mu = blocksum256(acc, rbuf, t) * (1.f / D);
    float d = acc - mu;
    float var = blocksum256(d * d, rbuf, t) * (1.f / D);
    float rstd = rsqrtf(var + 1e-5f);
    float y = d * rstd * ls[t] + lb[t];
    h[(size_t)n * D + t] = fmaxf(y, 0.f);
}

// ---------------------------------------------------------------- CSR build
__global__ __launch_bounds__(256) void count_k(const int* __restrict__ dst, int* __restrict__ deg, int E) {
    int e = blockIdx.x * 256 + threadIdx.x;
    if (e < E) atomicAdd(&deg[dst[e]], 1);
}

__global__ __launch_bounds__(1024) void scan_k(const int* __restrict__ deg, int* __restrict__ row_ptr,
                                               int* __restrict__ fill, int N) {
    __shared__ int sd[1024];
    int t = threadIdx.x;
    int chunk = (N + 1023) >> 10;
    int lo = t * chunk, hi = min(lo + chunk, N);
    int s = 0;
    for (int i = lo; i < hi; i++) s += deg[i];
    sd[t] = s;
    __syncthreads();
    for (int off = 1; off < 1024; off <<= 1) {
        int v = (t >= off) ? sd[t - off] : 0;
        __syncthreads();
        sd[t] += v;
        __syncthreads();
    }
    int run = (t > 0) ? sd[t - 1] : 0;
    for (int i = lo; i < hi; i++) {
        row_ptr[i] = run; fill[i] = run;
        run += deg[i];
    }
    if (t == 1023) row_ptr[N] = sd[1023];
}

__global__ __launch_bounds__(256) void scatter_k(const int* __restrict__ src, const int* __restrict__ dst,
                                                 int* __restrict__ fill, int* __restrict__ col, int E, int N) {
    int e = blockIdx.x * 256 + threadIdx.x;
    if (e < E) {
        int p = atomicAdd(&fill[dst[e]], 1);
        col[p] = src[e];
    } else if (e < E + N) {
        int n = e - E;
        int p = atomicAdd(&fill[n], 1);
        col[p] = n;                       // self loop
    }
}

// ---------------------------------------------------------------- weight repack for MFMA B-operand:
// Wp[mi][ct][ks][lane][j] (j=0..7 contiguous bf16) = W_mi[k = ks*32 + (lane>>4)*8 + j][n = ct*16 + (lane&15)]
// mi = layer*2 + (0:Wl, 1:Wr); per-matrix stride 16*8*64*8 = 65536 ushorts.
__global__ __launch_bounds__(256) void repack_k(const float* __restrict__ Wl, const float* __restrict__ Wr,
                                                unsigned short* __restrict__ Wp) {
    int tid = blockIdx.x * 256 + threadIdx.x;     // 98304 threads exactly
    int lane = tid & 63;
    int r1 = tid >> 6;
    int ks = r1 & 7;
    int r2 = r1 >> 3;
    int ct = r2 & 15;
    int mi = r2 >> 4;                              // 0..11
    int layer = mi >> 1, mat = mi & 1;
    const float* W = (mat == 0 ? Wl : Wr) + (size_t)layer * D * D;
    int n = ct * 16 + (lane & 15);
    int kb = ks * 32 + (lane >> 4) * 8;
    size_t base = (((size_t)(mi * 16 + ct) * 8 + ks) * 64 + lane) * 8;
#pragma unroll
    for (int j = 0; j < 8; j++) Wp[base + j] = f2bf(W[(size_t)(kb + j) * D + n]);
}

// ---------------------------------------------------------------- xl = h@Wl+bl, xr = h@Wr+br via MFMA.
// Block: 16 rows x 256 cols; 4 waves, wave w owns col-tiles w*4..w*4+3.
__global__ __launch_bounds__(256) void gemm_mfma_k(const float* __restrict__ h,
                                                   const unsigned short* __restrict__ WpL,
                                                   const unsigned short* __restrict__ WpR,
                                                   const float* __restrict__ bl, const float* __restrict__ br,
                                                   float* __restrict__ xl, float* __restrict__ xr, int N) {
    int t = threadIdx.x;
    int lane = t & 63;
    int w = t >> 6;
    int nb = blockIdx.x * 16;
    __shared__ unsigned short As[16][264];         // +8 pad: row stride 528B (16B-aligned, 2-way banks = free)
#pragma unroll
    for (int r = 0; r < 16; r++) {
        int row = nb + r;
        float v = (row < N) ? h[(size_t)row * D + t] : 0.f;
        As[r][t] = f2bf(v);
    }
    __syncthreads();
    int m = lane & 15;
    int q = lane >> 4;
    int ctbase = w * 4;
    f32x4 accL[4], accR[4];
#pragma unroll
    for (int ct = 0; ct < 4; ct++) {
        float bLv = bl[(ctbase + ct) * 16 + m];
        float bRv = br[(ctbase + ct) * 16 + m];
        accL[ct] = (f32x4){bLv, bLv, bLv, bLv};
        accR[ct] = (f32x4){bRv, bRv, bRv, bRv};
    }
#pragma unroll 2
    for (int ks = 0; ks < 8; ks++) {
        bfrag af = *(const bfrag*)&As[m][ks * 32 + q * 8];
#pragma unroll
        for (int ct = 0; ct < 4; ct++) {
            int ctg = ctbase + ct;
            size_t off = (((size_t)ctg * 8 + ks) * 64 + lane) * 8;
            bfrag bL = *(const bfrag*)&WpL[off];
            bfrag bR = *(const bfrag*)&WpR[off];
            accL[ct] = __builtin_amdgcn_mfma_f32_16x16x32_bf16(af, bL, accL[ct], 0, 0, 0);
            accR[ct] = __builtin_amdgcn_mfma_f32_16x16x32_bf16(af, bR, accR[ct], 0, 0, 0);
        }
    }
    // D layout: col = lane&15, row = (lane>>4)*4 + reg
#pragma unroll
    for (int ct = 0; ct < 4; ct++) {
        int colg = (ctbase + ct) * 16 + m;
#pragma unroll
        for (int reg = 0; reg < 4; reg++) {
            int row = nb + q * 4 + reg;
            if (row < N) {
                xl[(size_t)row * D + colg] = accL[ct][reg];
                xr[(size_t)row * D + colg] = accR[ct][reg];
            }
        }
    }
}

// ---------------------------------------------------------------- fused GATv2: ONE WAVE per dst node.
__global__ __launch_bounds__(256) void attn_k(const float* __restrict__ xl, const float* __restrict__ xr,
                                              const int* __restrict__ row_ptr, const int* __restrict__ col,
                                              const float* __restrict__ att, const float* __restrict__ gb,
                                              const float* __restrict__ gls, const float* __restrict__ glb,
                                              float* __restrict__ h, int layer, int N) {
    int t = threadIdx.x;
    int lane = t & 63;
    int n = blockIdx.x * 4 + (t >> 6);
    if (n >= N) return;
    int c4 = lane * 4;
    float4 xrv = *(const float4*)&xr[(size_t)n * D + c4];
    float4 av  = *(const float4*)&att[c4];
    int beg = row_ptr[n], end = row_ptr[n + 1];
    float m = -3.0e38f, l = 0.f;
    float4 acc = make_float4(0.f, 0.f, 0.f, 0.f);
    int src = col[beg];
    float4 xlv = *(const float4*)&xl[(size_t)src * D + c4];
    for (int e = beg; e < end; e++) {
        float4 nxt;
        if (e + 1 < end) {
            int nsrc = col[e + 1];
            nxt = *(const float4*)&xl[(size_t)nsrc * D + c4];
        }
        float sx = xlv.x + xrv.x; sx = sx > 0.f ? sx : NEG * sx;
        float sy = xlv.y + xrv.y; sy = sy > 0.f ? sy : NEG * sy;
        float sz = xlv.z + xrv.z; sz = sz > 0.f ? sz : NEG * sz;
        float sw = xlv.w + xrv.w; sw = sw > 0.f ? sw : NEG * sw;
        float z = av.x * sx + av.y * sy + av.z * sz + av.w * sw;
        z += __shfl_xor(z, 1); z += __shfl_xor(z, 2); z += __shfl_xor(z, 4);
        float mn = fmaxf(m, z);
        float sc = __expf(m - mn);
        float p  = __expf(z - mn);
        l = l * sc + p;
        acc.x = acc.x * sc + p * xlv.x;
        acc.y = acc.y * sc + p * xlv.y;
        acc.z = acc.z * sc + p * xlv.z;
        acc.w = acc.w * sc + p * xlv.w;
        m = mn;
        xlv = nxt;
    }
    float4 gbv  = *(const float4*)&gb[c4];
    float rl = 1.f / l;
    float4 o = make_float4(acc.x * rl + gbv.x, acc.y * rl + gbv.y,
                           acc.z * rl + gbv.z, acc.w * rl + gbv.w);
    float s = o.x + o.y + o.z + o.w;
#pragma unroll
    for (int msk = 1; msk <= 32; msk <<= 1) s += __shfl_xor(s, msk);
    float mu = s * (1.f / D);
    float4 dv = make_float4(o.x - mu, o.y - mu, o.z - mu, o.w - mu);
    float v2 = dv.x * dv.x + dv.y * dv.y + dv.z * dv.z + dv.w * dv.w;
#pragma unroll
    for (int msk = 1; msk <= 32; msk <<= 1) v2 += __shfl_xor(v2, msk);
    float rstd = rsqrtf(v2 * (1.f / D) + 1e-5f);
    float4 glsv = *(const float4*)&gls[c4];
    float4 glbv = *(const float4*)&glb[c4];
    float y0 = dv.x * rstd * glsv.x + glbv.x;
    float y1 = dv.y * rstd * glsv.y + glbv.y;
    float y2 = dv.z * rstd * glsv.z + glbv.z;
    float y3 = dv.w * rstd * glsv.w + glbv.w;
    y0 = y0 > 0.f ? y0 : expm1f(y0);
    y1 = y1 > 0.f ? y1 : expm1f(y1);
    y2 = y2 > 0.f ? y2 : expm1f(y2);
    y3 = y3 > 0.f ? y3 : expm1f(y3);
    float4 prev = make_float4(0.f, 0.f, 0.f, 0.f);
    if (layer > 0) prev = *(const float4*)&h[(size_t)n * D + c4];
    float4 res = make_float4(prev.x + y0, prev.y + y1, prev.z + y2, prev.w + y3);
    *(float4*)&h[(size_t)n * D + c4] = res;
}

// ---------------------------------------------------------------- per-node color head MLP (16 nodes/block)
__global__ __launch_bounds__(256) void color_k(const float* __restrict__ h,
                                               const float* __restrict__ W1, const float* __restrict__ b1,
                                               const float* __restrict__ W2, const float* __restrict__ b2,
                                               const float* __restrict__ W3, const float* __restrict__ b3,
                                               float* __restrict__ out, int N) {
    int t = threadIdx.x;
    int nb = blockIdx.x * 16;
    int nmax = min(16, N - nb);
    __shared__ float hs[16][D];
    __shared__ float z1[16][D];
    __shared__ float z2[16][128];
#pragma unroll
    for (int r = 0; r < 16; r++) hs[r][t] = (r < nmax) ? h[(size_t)(nb + r) * D + t] : 0.f;
    __syncthreads();
    float a[16];
    {
        float bv = b1[t];
#pragma unroll
        for (int r = 0; r < 16; r++) a[r] = bv;
        for (int k = 0; k < D; k += 4) {
            float w0 = W1[(k + 0) * D + t];
            float w1 = W1[(k + 1) * D + t];
            float w2 = W1[(k + 2) * D + t];
            float w3 = W1[(k + 3) * D + t];
#pragma unroll
            for (int r = 0; r < 16; r++) {
                float4 hv = *(const float4*)&hs[r][k];
                a[r] = fmaf(hv.x, w0, a[r]);
                a[r] = fmaf(hv.y, w1, a[r]);
                a[r] = fmaf(hv.z, w2, a[r]);
                a[r] = fmaf(hv.w, w3, a[r]);
            }
        }
#pragma unroll
        for (int r = 0; r < 16; r++) z1[r][t] = fmaxf(a[r], 0.f);
    }
    __syncthreads();
    if (t < 128) {
        float bv = b2[t];
#pragma unroll
        for (int r = 0; r < 16; r++) a[r] = bv;
        for (int k = 0; k < D; k += 4) {
            float w0 = W2[(k + 0) * 128 + t];
            float w1 = W2[(k + 1) * 128 + t];
            float w2 = W2[(k + 2) * 128 + t];
            float w3 = W2[(k + 3) * 128 + t];
#pragma unroll
            for (int r = 0; r < 16; r++) {
                float4 zv = *(const float4*)&z1[r][k];
                a[r] = fmaf(zv.x, w0, a[r]);
                a[r] = fmaf(zv.y, w1, a[r]);
                a[r] = fmaf(zv.z, w2, a[r]);
                a[r] = fmaf(zv.w, w3, a[r]);
            }
        }
#pragma unroll
        for (int r = 0; r < 16; r++) z2[r][t] = fmaxf(a[r], 0.f);
    }
    __syncthreads();
    if (t < MC) {
        float bv = b3[t];
#pragma unroll
        for (int r = 0; r < 16; r++) a[r] = bv;
        for (int k = 0; k < 128; k += 4) {
            float w0 = W3[(k + 0) * MC + t];
            float w1 = W3[(k + 1) * MC + t];
            float w2 = W3[(k + 2) * MC + t];
            float w3 = W3[(k + 3) * MC + t];
#pragma unroll
            for (int r = 0; r < 16; r++) {
                float4 zv = *(const float4*)&z2[r][k];
                a[r] = fmaf(zv.x, w0, a[r]);
                a[r] = fmaf(zv.y, w1, a[r]);
                a[r] = fmaf(zv.z, w2, a[r]);
                a[r] = fmaf(zv.w, w3, a[r]);
            }
        }
#pragma unroll
        for (int r = 0; r < 16; r++) {
            if (r < nmax) out[(size_t)(nb + r) * MC + t] = a[r];
        }
    }
}

// ---------------------------------------------------------------- pooling stage 1
__global__ __launch_bounds__(256) void pool_k(const float* __restrict__ h, const int* __restrict__ batch,
                                              float* __restrict__ psum, float* __restrict__ pmax,
                                              int* __restrict__ cnt, int N) {
    int b = blockIdx.x;
    int sl = blockIdx.y;
    int c = threadIdx.x;
    int lo = 0, hi = N;
    while (lo < hi) { int mid = (lo + hi) >> 1; if (batch[mid] < b) lo = mid + 1; else hi = mid; }
    int s0 = lo;
    lo = 0; hi = N;
    while (lo < hi) { int mid = (lo + hi) >> 1; if (batch[mid] < b + 1) lo = mid + 1; else hi = mid; }
    int s1 = lo;
    int len = s1 - s0;
    int chunk = (len + PS - 1) / PS;
    int n0 = s0 + sl * chunk;
    int n1 = min(n0 + chunk, s1);
    float sum = 0.f, mx = -3.0e38f;
    for (int n = n0; n < n1; n++) {
        float v = h[(size_t)n * D + c];
        sum += v;
        mx = fmaxf(mx, v);
    }
    psum[(size_t)(b * PS + sl) * D + c] = sum;
    pmax[(size_t)(b * PS + sl) * D + c] = mx;
    if (c == 0 && sl == 0) cnt[b] = len;
}

// ---------------------------------------------------------------- graph heads: grid (graph, section)
__global__ __launch_bounds__(256) void heads_k(const float* __restrict__ psum, const float* __restrict__ pmax,
                                               const int* __restrict__ cnt,
                                               const float* __restrict__ chW1, const float* __restrict__ chb1,
                                               const float* __restrict__ chW2, const float* __restrict__ chb2,
                                               const float* __restrict__ chW3, const float* __restrict__ chb3,
                                               const float* __restrict__ tW1, const float* __restrict__ tb1,
                                               const float* __restrict__ tW2, const float* __restrict__ tb2,
                                               const float* __restrict__ dW1, const float* __restrict__ db1,
                                               const float* __restrict__ dW2, const float* __restrict__ db2,
                                               float* __restrict__ out_ch, float* __restrict__ out_t,
                                               float* __restrict__ out_d) {
    int b = blockIdx.x, sec = blockIdx.y, t = threadIdx.x;
    __shared__ float g[2 * D];
    __shared__ float z1[D];
    __shared__ float z2[128];
    float sum = 0.f, mx = -3.0e38f;
#pragma unroll
    for (int sl = 0; sl < PS; sl++) {
        sum += psum[(size_t)(b * PS + sl) * D + t];
        mx = fmaxf(mx, pmax[(size_t)(b * PS + sl) * D + t]);
    }
    int cn = cnt[b];
    float c = fmaxf((float)cn, 1.f);
    g[t] = sum / c;
    g[D + t] = (cn > 0) ? mx : 0.f;
    __syncthreads();
    if (sec == 0) {
        // chromatic: 512 -> 256 -> 128 -> MC
        z1[t] = fmaxf(chb1[t] + dot_ilp(g, chW1, 2 * D, D, t), 0.f);
        __syncthreads();
        if (t < 128) z2[t] = fmaxf(chb2[t] + dot_ilp(z1, chW2, D, 128, t), 0.f);
        __syncthreads();
        if (t < MC) out_ch[b * MC + t] = chb3[t] + dot_ilp(z2, chW3, 128, MC, t);
    } else if (sec == 1) {
        // type: 512 -> 128 -> NT
        if (t < 128) z1[t] = fmaxf(tb1[t] + dot_ilp(g, tW1, 2 * D, 128, t), 0.f);
        __syncthreads();
        if (t < NT) out_t[b * NT + t] = tb2[t] + dot_ilp(z1, tW2, 128, NT, t);
    } else {
        // difficulty: 512 -> 64 -> 1, sigmoid*100
        if (t < 64) z1[t] = fmaxf(db1[t] + dot_ilp(g, dW1, 2 * D, 64, t), 0.f);
        __syncthreads();
        if (t == 0) {
            float a = db2[0] + dot_ilp(z1, dW2, 64, 1, 0);
            out_d[b] = 100.f / (1.f + __expf(-a));
        }
    }
}

// ----------------------------------------------------------------
extern "C" void kernel_launch(void* const* d_in, const int* in_sizes, int n_in,
                              void* d_out, int out_size, void* d_ws, size_t ws_size,
                              hipStream_t stream) {
    const float* x     = (const float*)d_in[0];
    const int*   ei    = (const int*)d_in[1];
    const int*   batch = (const int*)d_in[2];
    const float* encW  = (const float*)d_in[3];
    const float* encb  = (const float*)d_in[4];
    const float* encls = (const float*)d_in[5];
    const float* enclb = (const float*)d_in[6];
    const float* Wl    = (const float*)d_in[7];
    const float* bl    = (const float*)d_in[8];
    const float* Wr    = (const float*)d_in[9];
    const float* br    = (const float*)d_in[10];
    const float* att   = (const float*)d_in[11];
    const float* gb    = (const float*)d_in[12];
    const float* gls   = (const float*)d_in[13];
    const float* glb   = (const float*)d_in[14];
    const float* cW1   = (const float*)d_in[15];
    const float* cb1   = (const float*)d_in[16];
    const float* cW2   = (const float*)d_in[17];
    const float* cb2   = (const float*)d_in[18];
    const float* cW3   = (const float*)d_in[19];
    const float* cb3   = (const float*)d_in[20];
    const float* chW1  = (const float*)d_in[21];
    const float* chb1  = (const float*)d_in[22];
    const float* chW2  = (const float*)d_in[23];
    const float* chb2  = (const float*)d_in[24];
    const float* chW3  = (const float*)d_in[25];
    const float* chb3  = (const float*)d_in[26];
    const float* tW1   = (const float*)d_in[27];
    const float* tb1   = (const float*)d_in[28];
    const float* tW2   = (const float*)d_in[29];
    const float* tb2   = (const float*)d_in[30];
    const float* dW1   = (const float*)d_in[31];
    const float* db1   = (const float*)d_in[32];
    const float* dW2   = (const float*)d_in[33];
    const float* db2   = (const float*)d_in[34];

    const int N = in_sizes[0] / DIN;
    const int E = in_sizes[1] / 2;
    const int* esrc = ei;
    const int* edst = ei + E;

    char* p = (char*)d_ws;
    auto carve = [&](size_t bytes) { char* r = p; p += (bytes + 255) & ~(size_t)255; return r; };
    int*            row_ptr = (int*)carve((size_t)(N + 1) * 4);
    int*            fill    = (int*)carve((size_t)N * 4);
    int*            deg     = (int*)carve((size_t)N * 4);
    int*            cnt     = (int*)carve((size_t)BG * 4);
    float*          psum    = (float*)carve((size_t)BG * PS * D * 4);
    float*          pmax    = (float*)carve((size_t)BG * PS * D * 4);
    int*            col     = (int*)carve((size_t)(E + N) * 4);
    unsigned short* Wp      = (unsigned short*)carve((size_t)NL * 2 * 65536 * 2);
    float*          h       = (float*)carve((size_t)N * D * 4);
    float*          xl      = (float*)carve((size_t)N * D * 4);
    float*          xr      = (float*)carve((size_t)N * D * 4);
    (void)ws_size; (void)n_in; (void)out_size;

    init_k<<<(N + 255) / 256, 256, 0, stream>>>(deg, N);
    enc_k<<<N, 256, 0, stream>>>(x, encW, encb, encls, enclb, h, N);
    count_k<<<(E + 255) / 256, 256, 0, stream>>>(edst, deg, E);
    scan_k<<<1, 1024, 0, stream>>>(deg, row_ptr, fill, N);
    scatter_k<<<(E + N + 255) / 256, 256, 0, stream>>>(esrc, edst, fill, col, E, N);
    repack_k<<<384, 256, 0, stream>>>(Wl, Wr, Wp);

    for (int i = 0; i < NL; i++) {
        const unsigned short* WpL = Wp + (size_t)(i * 2 + 0) * 65536;
        const unsigned short* WpR = Wp + (size_t)(i * 2 + 1) * 65536;
        gemm_mfma_k<<<(N + 15) / 16, 256, 0, stream>>>(h, WpL, WpR, bl + i * D, br + i * D, xl, xr, N);
        attn_k<<<(N + 3) / 4, 256, 0, stream>>>(xl, xr, row_ptr, col, att + i * NH * NC,
                                                gb + i * D, gls + i * D, glb + i * D, h, i, N);
    }

    float* out = (float*)d_out;
    color_k<<<(N + 15) / 16, 256, 0, stream>>>(h, cW1, cb1, cW2, cb2, cW3, cb3, out, N);
    pool_k<<<dim3(BG, PS), 256, 0, stream>>>(h, batch, psum, pmax, cnt, N);
    heads_k<<<dim3(BG, 3), 256, 0, stream>>>(psum, pmax, cnt, chW1, chb1, chW2, chb2, chW3, chb3,
                                             tW1, tb1, tW2, tb2, dW1, db1, dW2, db2,
                                             out + (size_t)N * MC,
                                             out + (size_t)N * MC + BG * MC,
                                             out + (size_t)N * MC + BG * MC + BG * NT);
}

// Round 8
// 485.220 us; speedup vs baseline: 2.3097x; 1.1324x over previous
//
#include <hip/hip_runtime.h>
#include <hip/hip_bf16.h>

constexpr int DIN = 16;
constexpr int D   = 256;
constexpr int NH  = 8;
constexpr int NC  = 32;
constexpr int MC  = 200;
constexpr int NT  = 8;
constexpr int BG  = 16;
constexpr int NL  = 6;
constexpr int PS  = 16;   // pool slices per graph
constexpr float NEG = 0.2f;

typedef __attribute__((ext_vector_type(8))) short bfrag;   // 8 bf16 (4 VGPRs)
typedef __attribute__((ext_vector_type(4))) float f32x4;   // MFMA acc

// fp32 -> bf16 (RNE), bit-level
__device__ inline unsigned short f2bf(float f) {
    unsigned int u = __float_as_uint(f);
    u += 0x7FFFu + ((u >> 16) & 1u);
    return (unsigned short)(u >> 16);
}
__device__ inline float bf2f(unsigned short u) {
    return __uint_as_float((unsigned int)u << 16);
}

// block-wide (256-thread) sum, LDS tree, result broadcast to all threads.
__device__ inline float blocksum256(float v, float* rbuf, int t) {
    __syncthreads();
    rbuf[t] = v;
    __syncthreads();
    if (t < 128) rbuf[t] += rbuf[t + 128]; __syncthreads();
    if (t < 64)  rbuf[t] += rbuf[t + 64];  __syncthreads();
    if (t < 32)  rbuf[t] += rbuf[t + 32];  __syncthreads();
    if (t < 16)  rbuf[t] += rbuf[t + 16];  __syncthreads();
    if (t < 8)   rbuf[t] += rbuf[t + 8];   __syncthreads();
    if (t < 4)   rbuf[t] += rbuf[t + 4];   __syncthreads();
    if (t < 2)   rbuf[t] += rbuf[t + 2];   __syncthreads();
    if (t < 1)   rbuf[t] += rbuf[t + 1];   __syncthreads();
    float r = rbuf[0];
    __syncthreads();
    return r;
}

// ILP-4 dot
__device__ inline float dot_ilp(const float* __restrict__ g, const float* __restrict__ W,
                                int K, int ldw, int t) {
    float a0 = 0.f, a1 = 0.f, a2 = 0.f, a3 = 0.f;
    for (int k = 0; k < K; k += 4) {
        a0 = fmaf(g[k + 0], W[(k + 0) * ldw + t], a0);
        a1 = fmaf(g[k + 1], W[(k + 1) * ldw + t], a1);
        a2 = fmaf(g[k + 2], W[(k + 2) * ldw + t], a2);
        a3 = fmaf(g[k + 3], W[(k + 3) * ldw + t], a3);
    }
    return (a0 + a1) + (a2 + a3);
}

// ---------------------------------------------------------------- init
__global__ __launch_bounds__(256) void init_k(int* __restrict__ deg, int N) {
    int i = blockIdx.x * 256 + threadIdx.x;
    if (i < N) deg[i] = 1;                 // self-loop pre-counted
}

// ---------------------------------------------------------------- encoder: h = relu(LN(x@W+b))
__global__ __launch_bounds__(256) void enc_k(const float* __restrict__ x, const float* __restrict__ W,
                                             const float* __restrict__ b, const float* __restrict__ ls,
                                             const float* __restrict__ lb, float* __restrict__ h, int N) {
    int n = blockIdx.x, t = threadIdx.x;
    __shared__ float xs[DIN];
    __shared__ float rbuf[256];
    if (t < DIN) xs[t] = x[n * DIN + t];
    __syncthreads();
    float acc = b[t];
#pragma unroll
    for (int k = 0; k < DIN; k++) acc = fmaf(xs[k], W[k * D + t], acc);
    float mu = blocksum256(acc, rbuf, t) * (1.f / D);
    float d = acc - mu;
    float var = blocksum256(d * d, rbuf, t) * (1.f / D);
    float rstd = rsqrtf(var + 1e-5f);
    float y = d * rstd * ls[t] + lb[t];
    h[(size_t)n * D + t] = fmaxf(y, 0.f);
}

// ---------------------------------------------------------------- CSR build
__global__ __launch_bounds__(256) void count_k(const int* __restrict__ dst, int* __restrict__ deg, int E) {
    int e = blockIdx.x * 256 + threadIdx.x;
    if (e < E) atomicAdd(&deg[dst[e]], 1);
}

__global__ __launch_bounds__(1024) void scan_k(const int* __restrict__ deg, int* __restrict__ row_ptr,
                                               int* __restrict__ fill, int N) {
    __shared__ int sd[1024];
    int t = threadIdx.x;
    int chunk = (N + 1023) >> 10;
    int lo = t * chunk, hi = min(lo + chunk, N);
    int s = 0;
    for (int i = lo; i < hi; i++) s += deg[i];
    sd[t] = s;
    __syncthreads();
    for (int off = 1; off < 1024; off <<= 1) {
        int v = (t >= off) ? sd[t - off] : 0;
        __syncthreads();
        sd[t] += v;
        __syncthreads();
    }
    int run = (t > 0) ? sd[t - 1] : 0;
    for (int i = lo; i < hi; i++) {
        row_ptr[i] = run; fill[i] = run;
        run += deg[i];
    }
    if (t == 1023) row_ptr[N] = sd[1023];
}

__global__ __launch_bounds__(256) void scatter_k(const int* __restrict__ src, const int* __restrict__ dst,
                                                 int* __restrict__ fill, int* __restrict__ col, int E, int N) {
    int e = blockIdx.x * 256 + threadIdx.x;
    if (e < E) {
        int p = atomicAdd(&fill[dst[e]], 1);
        col[p] = src[e];
    } else if (e < E + N) {
        int n = e - E;
        int p = atomicAdd(&fill[n], 1);
        col[p] = n;                       // self loop
    }
}

// ---------------------------------------------------------------- repack attn weights (B-fragment layout)
// Wp[mi][ct][ks][lane][j] = W_mi[k = ks*32+(lane>>4)*8+j][n = ct*16+(lane&15)]
__global__ __launch_bounds__(256) void repack_k(const float* __restrict__ Wl, const float* __restrict__ Wr,
                                                unsigned short* __restrict__ Wp) {
    int tid = blockIdx.x * 256 + threadIdx.x;     // 98304 threads exactly
    int lane = tid & 63;
    int r1 = tid >> 6;
    int ks = r1 & 7;
    int r2 = r1 >> 3;
    int ct = r2 & 15;
    int mi = r2 >> 4;                              // 0..11
    int layer = mi >> 1, mat = mi & 1;
    const float* W = (mat == 0 ? Wl : Wr) + (size_t)layer * D * D;
    int n = ct * 16 + (lane & 15);
    int kb = ks * 32 + (lane >> 4) * 8;
    size_t base = (((size_t)(mi * 16 + ct) * 8 + ks) * 64 + lane) * 8;
#pragma unroll
    for (int j = 0; j < 8; j++) Wp[base + j] = f2bf(W[(size_t)(kb + j) * D + n]);
}

// generic repack: K x NCOL (row-major) -> nct x nks fragment tiles, zero-padded
__global__ __launch_bounds__(256) void repack_c(const float* __restrict__ W, unsigned short* __restrict__ Wp,
                                                int K, int NCOL, int nct, int nks) {
    int tid = blockIdx.x * 256 + threadIdx.x;
    int total = nct * nks * 64;
    if (tid >= total) return;
    int lane = tid & 63;
    int r = tid >> 6;
    int ks = r % nks;
    int ct = r / nks;
    int n = ct * 16 + (lane & 15);
    int kb = ks * 32 + (lane >> 4) * 8;
    size_t base = (((size_t)ct * nks + ks) * 64 + lane) * 8;
#pragma unroll
    for (int j = 0; j < 8; j++) {
        int k = kb + j;
        Wp[base + j] = (n < NCOL && k < K) ? f2bf(W[(size_t)k * NCOL + n]) : (unsigned short)0;
    }
}

// ---------------------------------------------------------------- xl = h@Wl+bl, xr = h@Wr+br via MFMA (bf16 out)
__global__ __launch_bounds__(256) void gemm_mfma_k(const float* __restrict__ h,
                                                   const unsigned short* __restrict__ WpL,
                                                   const unsigned short* __restrict__ WpR,
                                                   const float* __restrict__ bl, const float* __restrict__ br,
                                                   unsigned short* __restrict__ xl, unsigned short* __restrict__ xr,
                                                   int N) {
    int t = threadIdx.x;
    int lane = t & 63;
    int w = t >> 6;
    int nb = blockIdx.x * 16;
    __shared__ unsigned short As[16][264];         // +8 pad
#pragma unroll
    for (int r = 0; r < 16; r++) {
        int row = nb + r;
        float v = (row < N) ? h[(size_t)row * D + t] : 0.f;
        As[r][t] = f2bf(v);
    }
    __syncthreads();
    int m = lane & 15;
    int q = lane >> 4;
    int ctbase = w * 4;
    f32x4 accL[4], accR[4];
#pragma unroll
    for (int ct = 0; ct < 4; ct++) {
        float bLv = bl[(ctbase + ct) * 16 + m];
        float bRv = br[(ctbase + ct) * 16 + m];
        accL[ct] = (f32x4){bLv, bLv, bLv, bLv};
        accR[ct] = (f32x4){bRv, bRv, bRv, bRv};
    }
#pragma unroll 2
    for (int ks = 0; ks < 8; ks++) {
        bfrag af = *(const bfrag*)&As[m][ks * 32 + q * 8];
#pragma unroll
        for (int ct = 0; ct < 4; ct++) {
            int ctg = ctbase + ct;
            size_t off = (((size_t)ctg * 8 + ks) * 64 + lane) * 8;
            bfrag bL = *(const bfrag*)&WpL[off];
            bfrag bR = *(const bfrag*)&WpR[off];
            accL[ct] = __builtin_amdgcn_mfma_f32_16x16x32_bf16(af, bL, accL[ct], 0, 0, 0);
            accR[ct] = __builtin_amdgcn_mfma_f32_16x16x32_bf16(af, bR, accR[ct], 0, 0, 0);
        }
    }
    // D layout: col = lane&15, row = (lane>>4)*4 + reg
#pragma unroll
    for (int ct = 0; ct < 4; ct++) {
        int colg = (ctbase + ct) * 16 + m;
#pragma unroll
        for (int reg = 0; reg < 4; reg++) {
            int row = nb + q * 4 + reg;
            if (row < N) {
                xl[(size_t)row * D + colg] = f2bf(accL[ct][reg]);
                xr[(size_t)row * D + colg] = f2bf(accR[ct][reg]);
            }
        }
    }
}

// ---------------------------------------------------------------- fused GATv2: ONE WAVE per dst node (bf16 xl/xr)
__global__ __launch_bounds__(256) void attn_k(const unsigned short* __restrict__ xl,
                                              const unsigned short* __restrict__ xr,
                                              const int* __restrict__ row_ptr, const int* __restrict__ col,
                                              const float* __restrict__ att, const float* __restrict__ gb,
                                              const float* __restrict__ gls, const float* __restrict__ glb,
                                              float* __restrict__ h, int layer, int N) {
    int t = threadIdx.x;
    int lane = t & 63;
    int n = blockIdx.x * 4 + (t >> 6);
    if (n >= N) return;
    int c4 = lane * 4;
    ushort4 xr4 = *(const ushort4*)&xr[(size_t)n * D + c4];
    float4 xrv = make_float4(bf2f(xr4.x), bf2f(xr4.y), bf2f(xr4.z), bf2f(xr4.w));
    float4 av  = *(const float4*)&att[c4];
    int beg = row_ptr[n], end = row_ptr[n + 1];
    float m = -3.0e38f, l = 0.f;
    float4 acc = make_float4(0.f, 0.f, 0.f, 0.f);
    int src = col[beg];
    ushort4 x4 = *(const ushort4*)&xl[(size_t)src * D + c4];
    for (int e = beg; e < end; e++) {
        ushort4 nxt;
        if (e + 1 < end) {
            int nsrc = col[e + 1];
            nxt = *(const ushort4*)&xl[(size_t)nsrc * D + c4];
        }
        float4 xlv = make_float4(bf2f(x4.x), bf2f(x4.y), bf2f(x4.z), bf2f(x4.w));
        float sx = xlv.x + xrv.x; sx = sx > 0.f ? sx : NEG * sx;
        float sy = xlv.y + xrv.y; sy = sy > 0.f ? sy : NEG * sy;
        float sz = xlv.z + xrv.z; sz = sz > 0.f ? sz : NEG * sz;
        float sw = xlv.w + xrv.w; sw = sw > 0.f ? sw : NEG * sw;
        float z = av.x * sx + av.y * sy + av.z * sz + av.w * sw;
        z += __shfl_xor(z, 1); z += __shfl_xor(z, 2); z += __shfl_xor(z, 4);
        float mn = fmaxf(m, z);
        float sc = __expf(m - mn);
        float p  = __expf(z - mn);
        l = l * sc + p;
        acc.x = acc.x * sc + p * xlv.x;
        acc.y = acc.y * sc + p * xlv.y;
        acc.z = acc.z * sc + p * xlv.z;
        acc.w = acc.w * sc + p * xlv.w;
        m = mn;
        x4 = nxt;
    }
    float4 gbv  = *(const float4*)&gb[c4];
    float rl = 1.f / l;
    float4 o = make_float4(acc.x * rl + gbv.x, acc.y * rl + gbv.y,
                           acc.z * rl + gbv.z, acc.w * rl + gbv.w);
    float s = o.x + o.y + o.z + o.w;
#pragma unroll
    for (int msk = 1; msk <= 32; msk <<= 1) s += __shfl_xor(s, msk);
    float mu = s * (1.f / D);
    float4 dv = make_float4(o.x - mu, o.y - mu, o.z - mu, o.w - mu);
    float v2 = dv.x * dv.x + dv.y * dv.y + dv.z * dv.z + dv.w * dv.w;
#pragma unroll
    for (int msk = 1; msk <= 32; msk <<= 1) v2 += __shfl_xor(v2, msk);
    float rstd = rsqrtf(v2 * (1.f / D) + 1e-5f);
    float4 glsv = *(const float4*)&gls[c4];
    float4 glbv = *(const float4*)&glb[c4];
    float y0 = dv.x * rstd * glsv.x + glbv.x;
    float y1 = dv.y * rstd * glsv.y + glbv.y;
    float y2 = dv.z * rstd * glsv.z + glbv.z;
    float y3 = dv.w * rstd * glsv.w + glbv.w;
    y0 = y0 > 0.f ? y0 : expm1f(y0);
    y1 = y1 > 0.f ? y1 : expm1f(y1);
    y2 = y2 > 0.f ? y2 : expm1f(y2);
    y3 = y3 > 0.f ? y3 : expm1f(y3);
    float4 prev = make_float4(0.f, 0.f, 0.f, 0.f);
    if (layer > 0) prev = *(const float4*)&h[(size_t)n * D + c4];
    float4 res = make_float4(prev.x + y0, prev.y + y1, prev.z + y2, prev.w + y3);
    *(float4*)&h[(size_t)n * D + c4] = res;
}

// ---------------------------------------------------------------- fused color-head MLP via MFMA.
// 16 rows/block, 4 waves. relu activations round-trip via LDS as bf16 A-fragments.
__global__ __launch_bounds__(256) void color_mfma_k(const float* __restrict__ h,
                                                    const unsigned short* __restrict__ W1p, const float* __restrict__ b1,
                                                    const unsigned short* __restrict__ W2p, const float* __restrict__ b2,
                                                    const unsigned short* __restrict__ W3p, const float* __restrict__ b3,
                                                    float* __restrict__ out, int N) {
    int t = threadIdx.x;
    int lane = t & 63;
    int w = t >> 6;
    int nb = blockIdx.x * 16;
    __shared__ unsigned short As[16][264];
    __shared__ unsigned short Zs[16][264];
#pragma unroll
    for (int r = 0; r < 16; r++) {
        int row = nb + r;
        float v = (row < N) ? h[(size_t)row * D + t] : 0.f;
        As[r][t] = f2bf(v);
    }
    __syncthreads();
    int m = lane & 15;
    int q = lane >> 4;
    // layer1: 256 -> 256, 16 col-tiles, wave w -> tiles w*4..w*4+3. Zs = relu bf16.
    {
        f32x4 acc[4];
#pragma unroll
        for (int ct = 0; ct < 4; ct++) {
            float bv = b1[(w * 4 + ct) * 16 + m];
            acc[ct] = (f32x4){bv, bv, bv, bv};
        }
#pragma unroll 2
        for (int ks = 0; ks < 8; ks++) {
            bfrag af = *(const bfrag*)&As[m][ks * 32 + q * 8];
#pragma unroll
            for (int ct = 0; ct < 4; ct++) {
                int ctg = w * 4 + ct;
                bfrag bf = *(const bfrag*)&W1p[(((size_t)ctg * 8 + ks) * 64 + lane) * 8];
                acc[ct] = __builtin_amdgcn_mfma_f32_16x16x32_bf16(af, bf, acc[ct], 0, 0, 0);
            }
        }
#pragma unroll
        for (int ct = 0; ct < 4; ct++) {
            int colg = (w * 4 + ct) * 16 + m;
#pragma unroll
            for (int reg = 0; reg < 4; reg++)
                Zs[q * 4 + reg][colg] = f2bf(fmaxf(acc[ct][reg], 0.f));
        }
    }
    __syncthreads();
    // layer2: 256 -> 128, 8 col-tiles, wave w -> tiles w*2, w*2+1. As (cols 0..127) = relu bf16.
    {
        f32x4 acc[2];
#pragma unroll
        for (int ct = 0; ct < 2; ct++) {
            float bv = b2[(w * 2 + ct) * 16 + m];
            acc[ct] = (f32x4){bv, bv, bv, bv};
        }
#pragma unroll 2
        for (int ks = 0; ks < 8; ks++) {
            bfrag af = *(const bfrag*)&Zs[m][ks * 32 + q * 8];
#pragma unroll
            for (int ct = 0; ct < 2; ct++) {
                int ctg = w * 2 + ct;
                bfrag bf = *(const bfrag*)&W2p[(((size_t)ctg * 8 + ks) * 64 + lane) * 8];
                acc[ct] = __builtin_amdgcn_mfma_f32_16x16x32_bf16(af, bf, acc[ct], 0, 0, 0);
            }
        }
        __syncthreads();          // As no longer needed as input
#pragma unroll
        for (int ct = 0; ct < 2; ct++) {
            int colg = (w * 2 + ct) * 16 + m;
#pragma unroll
            for (int reg = 0; reg < 4; reg++)
                As[q * 4 + reg][colg] = f2bf(fmaxf(acc[ct][reg], 0.f));
        }
    }
    __syncthreads();
    // layer3: 128 -> 200 (13 tiles, padded to 208), wave w -> tiles w, w+4, w+8, (12 for w==0)
    for (int ctg = w; ctg < 13; ctg += 4) {
        int colg = ctg * 16 + m;
        float bv = (colg < MC) ? b3[colg] : 0.f;
        f32x4 acc = (f32x4){bv, bv, bv, bv};
#pragma unroll
        for (int ks = 0; ks < 4; ks++) {
            bfrag af = *(const bfrag*)&As[m][ks * 32 + q * 8];
            bfrag bf = *(const bfrag*)&W3p[(((size_t)ctg * 4 + ks) * 64 + lane) * 8];
            acc = __builtin_amdgcn_mfma_f32_16x16x32_bf16(af, bf, acc, 0, 0, 0);
        }
#pragma unroll
        for (int reg = 0; reg < 4; reg++) {
            int row = nb + q * 4 + reg;
            if (row < N && colg < MC) out[(size_t)row * MC + colg] = acc[reg];
        }
    }
}

// ---------------------------------------------------------------- pooling stage 1
__global__ __launch_bounds__(256) void pool_k(const float* __restrict__ h, const int* __restrict__ batch,
                                              float* __restrict__ psum, float* __restrict__ pmax,
                                              int* __restrict__ cnt, int N) {
    int b = blockIdx.x;
    int sl = blockIdx.y;
    int c = threadIdx.x;
    int lo = 0, hi = N;
    while (lo < hi) { int mid = (lo + hi) >> 1; if (batch[mid] < b) lo = mid + 1; else hi = mid; }
    int s0 = lo;
    lo = 0; hi = N;
    while (lo < hi) { int mid = (lo + hi) >> 1; if (batch[mid] < b + 1) lo = mid + 1; else hi = mid; }
    int s1 = lo;
    int len = s1 - s0;
    int chunk = (len + PS - 1) / PS;
    int n0 = s0 + sl * chunk;
    int n1 = min(n0 + chunk, s1);
    float sum = 0.f, mx = -3.0e38f;
    for (int n = n0; n < n1; n++) {
        float v = h[(size_t)n * D + c];
        sum += v;
        mx = fmaxf(mx, v);
    }
    psum[(size_t)(b * PS + sl) * D + c] = sum;
    pmax[(size_t)(b * PS + sl) * D + c] = mx;
    if (c == 0 && sl == 0) cnt[b] = len;
}

// ---------------------------------------------------------------- graph heads: grid (graph, section)
__global__ __launch_bounds__(256) void heads_k(const float* __restrict__ psum, const float* __restrict__ pmax,
                                               const int* __restrict__ cnt,
                                               const float* __restrict__ chW1, const float* __restrict__ chb1,
                                               const float* __restrict__ chW2, const float* __restrict__ chb2,
                                               const float* __restrict__ chW3, const float* __restrict__ chb3,
                                               const float* __restrict__ tW1, const float* __restrict__ tb1,
                                               const float* __restrict__ tW2, const float* __restrict__ tb2,
                                               const float* __restrict__ dW1, const float* __restrict__ db1,
                                               const float* __restrict__ dW2, const float* __restrict__ db2,
                                               float* __restrict__ out_ch, float* __restrict__ out_t,
                                               float* __restrict__ out_d) {
    int b = blockIdx.x, sec = blockIdx.y, t = threadIdx.x;
    __shared__ float g[2 * D];
    __shared__ float z1[D];
    __shared__ float z2[128];
    float sum = 0.f, mx = -3.0e38f;
#pragma unroll
    for (int sl = 0; sl < PS; sl++) {
        sum += psum[(size_t)(b * PS + sl) * D + t];
        mx = fmaxf(mx, pmax[(size_t)(b * PS + sl) * D + t]);
    }
    int cn = cnt[b];
    float c = fmaxf((float)cn, 1.f);
    g[t] = sum / c;
    g[D + t] = (cn > 0) ? mx : 0.f;
    __syncthreads();
    if (sec == 0) {
        z1[t] = fmaxf(chb1[t] + dot_ilp(g, chW1, 2 * D, D, t), 0.f);
        __syncthreads();
        if (t < 128) z2[t] = fmaxf(chb2[t] + dot_ilp(z1, chW2, D, 128, t), 0.f);
        __syncthreads();
        if (t < MC) out_ch[b * MC + t] = chb3[t] + dot_ilp(z2, chW3, 128, MC, t);
    } else if (sec == 1) {
        if (t < 128) z1[t] = fmaxf(tb1[t] + dot_ilp(g, tW1, 2 * D, 128, t), 0.f);
        __syncthreads();
        if (t < NT) out_t[b * NT + t] = tb2[t] + dot_ilp(z1, tW2, 128, NT, t);
    } else {
        if (t < 64) z1[t] = fmaxf(db1[t] + dot_ilp(g, dW1, 2 * D, 64, t), 0.f);
        __syncthreads();
        if (t == 0) {
            float a = db2[0] + dot_ilp(z1, dW2, 64, 1, 0);
            out_d[b] = 100.f / (1.f + __expf(-a));
        }
    }
}

// ----------------------------------------------------------------
extern "C" void kernel_launch(void* const* d_in, const int* in_sizes, int n_in,
                              void* d_out, int out_size, void* d_ws, size_t ws_size,
                              hipStream_t stream) {
    const float* x     = (const float*)d_in[0];
    const int*   ei    = (const int*)d_in[1];
    const int*   batch = (const int*)d_in[2];
    const float* encW  = (const float*)d_in[3];
    const float* encb  = (const float*)d_in[4];
    const float* encls = (const float*)d_in[5];
    const float* enclb = (const float*)d_in[6];
    const float* Wl    = (const float*)d_in[7];
    const float* bl    = (const float*)d_in[8];
    const float* Wr    = (const float*)d_in[9];
    const float* br    = (const float*)d_in[10];
    const float* att   = (const float*)d_in[11];
    const float* gb    = (const float*)d_in[12];
    const float* gls   = (const float*)d_in[13];
    const float* glb   = (const float*)d_in[14];
    const float* cW1   = (const float*)d_in[15];
    const float* cb1   = (const float*)d_in[16];
    const float* cW2   = (const float*)d_in[17];
    const float* cb2   = (const float*)d_in[18];
    const float* cW3   = (const float*)d_in[19];
    const float* cb3   = (const float*)d_in[20];
    const float* chW1  = (const float*)d_in[21];
    const float* chb1  = (const float*)d_in[22];
    const float* chW2  = (const float*)d_in[23];
    const float* chb2  = (const float*)d_in[24];
    const float* chW3  = (const float*)d_in[25];
    const float* chb3  = (const float*)d_in[26];
    const float* tW1   = (const float*)d_in[27];
    const float* tb1   = (const float*)d_in[28];
    const float* tW2   = (const float*)d_in[29];
    const float* tb2   = (const float*)d_in[30];
    const float* dW1   = (const float*)d_in[31];
    const float* db1   = (const float*)d_in[32];
    const float* dW2   = (const float*)d_in[33];
    const float* db2   = (const float*)d_in[34];

    const int N = in_sizes[0] / DIN;
    const int E = in_sizes[1] / 2;
    const int* esrc = ei;
    const int* edst = ei + E;

    char* p = (char*)d_ws;
    auto carve = [&](size_t bytes) { char* r = p; p += (bytes + 255) & ~(size_t)255; return r; };
    int*            row_ptr = (int*)carve((size_t)(N + 1) * 4);
    int*            fill    = (int*)carve((size_t)N * 4);
    int*            deg     = (int*)carve((size_t)N * 4);
    int*            cnt     = (int*)carve((size_t)BG * 4);
    float*          psum    = (float*)carve((size_t)BG * PS * D * 4);
    float*          pmax    = (float*)carve((size_t)BG * PS * D * 4);
    int*            col     = (int*)carve((size_t)(E + N) * 4);
    unsigned short* Wp      = (unsigned short*)carve((size_t)NL * 2 * 65536 * 2);
    unsigned short* cW1p    = (unsigned short*)carve((size_t)16 * 8 * 64 * 8 * 2);
    unsigned short* cW2p    = (unsigned short*)carve((size_t)8 * 8 * 64 * 8 * 2);
    unsigned short* cW3p    = (unsigned short*)carve((size_t)13 * 4 * 64 * 8 * 2);
    float*          h       = (float*)carve((size_t)N * D * 4);
    unsigned short* xl      = (unsigned short*)carve((size_t)N * D * 2);
    unsigned short* xr      = (unsigned short*)carve((size_t)N * D * 2);
    (void)ws_size; (void)n_in; (void)out_size;

    init_k<<<(N + 255) / 256, 256, 0, stream>>>(deg, N);
    enc_k<<<N, 256, 0, stream>>>(x, encW, encb, encls, enclb, h, N);
    count_k<<<(E + 255) / 256, 256, 0, stream>>>(edst, deg, E);
    scan_k<<<1, 1024, 0, stream>>>(deg, row_ptr, fill, N);
    scatter_k<<<(E + N + 255) / 256, 256, 0, stream>>>(esrc, edst, fill, col, E, N);
    repack_k<<<384, 256, 0, stream>>>(Wl, Wr, Wp);
    repack_c<<<32, 256, 0, stream>>>(cW1, cW1p, D, D, 16, 8);
    repack_c<<<16, 256, 0, stream>>>(cW2, cW2p, D, 128, 8, 8);
    repack_c<<<13, 256, 0, stream>>>(cW3, cW3p, 128, MC, 13, 4);

    for (int i = 0; i < NL; i++) {
        const unsigned short* WpL = Wp + (size_t)(i * 2 + 0) * 65536;
        const unsigned short* WpR = Wp + (size_t)(i * 2 + 1) * 65536;
        gemm_mfma_k<<<(N + 15) / 16, 256, 0, stream>>>(h, WpL, WpR, bl + i * D, br + i * D, xl, xr, N);
        attn_k<<<(N + 3) / 4, 256, 0, stream>>>(xl, xr, row_ptr, col, att + i * NH * NC,
                                                gb + i * D, gls + i * D, glb + i * D, h, i, N);
    }

    float* out = (float*)d_out;
    color_mfma_k<<<(N + 15) / 16, 256, 0, stream>>>(h, cW1p, cb1, cW2p, cb2, cW3p, cb3, out, N);
    pool_k<<<dim3(BG, PS), 256, 0, stream>>>(h, batch, psum, pmax, cnt, N);
    heads_k<<<dim3(BG, 3), 256, 0, stream>>>(psum, pmax, cnt, chW1, chb1, chW2, chb2, chW3, chb3,
                                             tW1, tb1, tW2, tb2, dW1, db1, dW2, db2,
                                             out + (size_t)N * MC,
                                             out + (size_t)N * MC + BG * MC,
                                             out + (size_t)N * MC + BG * MC + BG * NT);
}